// Round 2
// 175.911 us; speedup vs baseline: 1.0055x; 1.0055x over previous
//
#include <hip/hip_runtime.h>

#define NB   1024
#define SINQ 256
#define SPRQ 128
#define HIDQ 512

// pos_enc: emb[:, :3] = sin(pos * inv_freq[c]); inv_freq[c] = 10000^(-2c/256)
#define PEF1  0.93057207f
#define PEF2  0.86596438f
#define LOG2E 1.44269504089f
// q pre-scale: 1/sqrt(3) * log2(e)
#define QS    0.83298066476f

typedef _Float16 h2 __attribute__((ext_vector_type(2)));
typedef float    f2 __attribute__((ext_vector_type(2)));

#if defined(__has_builtin) && __has_builtin(__builtin_amdgcn_exp2f)
#define EXP2(x) __builtin_amdgcn_exp2f(x)
#else
#define EXP2(x) exp2f(x)
#endif

#if defined(__has_builtin) && __has_builtin(__builtin_amdgcn_fdot2)
#define FDOT2(a, b, c) __builtin_amdgcn_fdot2((a), (b), (c), false)
#else
__device__ __forceinline__ float fdot2_sw(h2 a, h2 b, float c) {
  return fmaf((float)a.x, (float)b.x, fmaf((float)a.y, (float)b.y, c));
}
#define FDOT2(a, b, c) fdot2_sw((a), (b), (c))
#endif

__device__ __forceinline__ unsigned pk16(float a, float b) {
  h2 v; v.x = (_Float16)a; v.y = (_Float16)b;
  return __builtin_bit_cast(unsigned, v);
}
__device__ __forceinline__ h2 uph(unsigned u) { return __builtin_bit_cast(h2, u); }

__device__ __forceinline__ h2 relu2(h2 z) {
#if defined(__has_builtin) && __has_builtin(__builtin_elementwise_max)
  h2 zz; zz.x = (_Float16)0.f; zz.y = (_Float16)0.f;
  return __builtin_elementwise_max(z, zz);
#else
  z.x = z.x > (_Float16)0.f ? z.x : (_Float16)0.f;
  z.y = z.y > (_Float16)0.f ? z.y : (_Float16)0.f;
  return z;
#endif
}

__device__ __forceinline__ f2 mkf2(float a, float b) { f2 r; r.x = a; r.y = b; return r; }
#if defined(__has_builtin) && __has_builtin(__builtin_elementwise_fma)
__device__ __forceinline__ f2 fma2(f2 a, f2 b, f2 c) {
  return __builtin_elementwise_fma(a, b, c);   // v_pk_fma_f32
}
#else
__device__ __forceinline__ f2 fma2(f2 a, f2 b, f2 c) {
  f2 r; r.x = fmaf(a.x, b.x, c.x); r.y = fmaf(a.y, b.y, c.y); return r;
}
#endif

// xor-combine over the 4 slot lanes of a quad (scalar / f2 variants).
// NOTE: R1 post-mortem — DPP (quad_perm/row_mirror) versions of these broke
// correctness (absmax 8.78); reverted to harness-proven __shfl_xor forms.
#define C4S(v)  { (v) += __shfl_xor((v), 1, 64); (v) += __shfl_xor((v), 2, 64); }
#define C4F2(v) { f2 _t; _t.x = __shfl_xor((v).x, 1, 64); _t.y = __shfl_xor((v).y, 1, 64); (v) += _t; \
                  _t.x = __shfl_xor((v).x, 2, 64); _t.y = __shfl_xor((v).y, 2, 64); (v) += _t; }

// register-only selects (v_cndmask chains) -- NEVER index private arrays
// with a runtime value: that demotes them to scratch (HBM!).
__device__ __forceinline__ float sel4(float a, float b, float c, float d, int s) {
  float r = a;
  r = (s == 1) ? b : r;
  r = (s == 2) ? c : r;
  r = (s == 3) ? d : r;
  return r;
}
__device__ __forceinline__ float sel2(float a, float b, int s) {
  return s ? b : a;
}

// Block-wide (256 thr) mean/rstd over nelem values.
__device__ __forceinline__ void block_stats(float s1, float s2, float* sRed,
                                            int tid, float nelem,
                                            float& mean, float& rstd) {
#pragma unroll
  for (int off = 32; off > 0; off >>= 1) {
    s1 += __shfl_xor(s1, off, 64);
    s2 += __shfl_xor(s2, off, 64);
  }
  __syncthreads();
  if ((tid & 63) == 0) {
    sRed[((tid >> 6) << 1) + 0] = s1;
    sRed[((tid >> 6) << 1) + 1] = s2;
  }
  __syncthreads();
  float t1 = sRed[0] + sRed[2] + sRed[4] + sRed[6];
  float t2 = sRed[1] + sRed[3] + sRed[5] + sRed[7];
  mean = t1 / nelem;
  rstd = rsqrtf(t2 / nelem - mean * mean + 1e-5f);
}

// Pack f16 FFN pair-records and the sin() table.
__global__ __launch_bounds__(256) void pack_tabs(
    const float* __restrict__ ew1, const float* __restrict__ eb1,
    const float* __restrict__ ew2,
    const float* __restrict__ dw1, const float* __restrict__ db1,
    const float* __restrict__ dw2,
    uint4* __restrict__ fE, uint4* __restrict__ fD, float4* __restrict__ pe)
{
  const int t = threadIdx.x;        // pair index, 0..255
  const int k0 = 2 * t, k1 = 2 * t + 1;
  fE[2 * t] = make_uint4(pk16(ew1[3 * k0], ew1[3 * k1]),
                         pk16(ew1[3 * k0 + 1], ew1[3 * k1 + 1]),
                         pk16(ew1[3 * k0 + 2], ew1[3 * k1 + 2]),
                         pk16(eb1[k0], eb1[k1]));
  fE[2 * t + 1] = make_uint4(pk16(ew2[k0], ew2[k1]),
                             pk16(ew2[HIDQ + k0], ew2[HIDQ + k1]),
                             pk16(ew2[2 * HIDQ + k0], ew2[2 * HIDQ + k1]), 0u);
  fD[2 * t] = make_uint4(pk16(dw1[3 * k0], dw1[3 * k1]),
                         pk16(dw1[3 * k0 + 1], dw1[3 * k1 + 1]),
                         pk16(dw1[3 * k0 + 2], dw1[3 * k1 + 2]),
                         pk16(db1[k0], db1[k1]));
  fD[2 * t + 1] = make_uint4(pk16(dw2[k0], dw2[k1]),
                             pk16(dw2[HIDQ + k0], dw2[HIDQ + k1]),
                             pk16(dw2[2 * HIDQ + k0], dw2[2 * HIDQ + k1]), 0u);
  const float p = (float)t;
  pe[t] = make_float4(sinf(p), sinf(p * PEF1), sinf(p * PEF2), 0.f);
}

// One 256-thr block per batch element. 4-way slot-split (s = t&3) over j/k,
// Q=4 rows/thread (enc) and Q=2 (dec); combines via shfl_xor quad reduces.
// Attention rows/keys kept in f32 float4 LDS (p0,p1,p2,1): score = pk_mul +
// v_pk_fma_f32 + add; accumulate (a0,a1),(a2,dn) as 2x v_pk_fma_f32.
__global__ __launch_bounds__(256, 4) void fused_fwd(
    const float* __restrict__ X, const float* __restrict__ T,
    const float* __restrict__ einw, const float* __restrict__ einb,
    const float* __restrict__ eow,  const float* __restrict__ eob,
    const float* __restrict__ eln1w, const float* __restrict__ eln1b,
    const float* __restrict__ eb2,
    const float* __restrict__ eln2w, const float* __restrict__ eln2b,
    const float* __restrict__ a1w, const float* __restrict__ a1b,
    const float* __restrict__ a1ow, const float* __restrict__ a1ob,
    const float* __restrict__ dln1w, const float* __restrict__ dln1b,
    const float* __restrict__ a2w, const float* __restrict__ a2b,
    const float* __restrict__ a2ow, const float* __restrict__ a2ob,
    const float* __restrict__ db2,
    const float* __restrict__ dln3w, const float* __restrict__ dln3b,
    const uint4* __restrict__ fE, const uint4* __restrict__ fD,
    const float4* __restrict__ pe,
    float* __restrict__ out)
{
  __shared__ uint4  sFE[2 * 256];   // 8 KB enc FFN pair-records
  __shared__ uint4  sFD[2 * 256];   // 8 KB dec FFN pair-records
  __shared__ float4 sEP[SINQ];      // 4 KB f32 p_X rows (p0,p1,p2,1)
  __shared__ float4 sDP[SPRQ];      // 2 KB f32 p_T rows
  __shared__ float4 sCE[SINQ];      // 4 KB f32 enc_out rows
  __shared__ float  sRed[8];

  const int b = blockIdx.x;
  const int t = threadIdx.x;
  const int lane = t & 63;
  const int s = t & 3;             // slot
  const int g = t >> 2;            // enc row-group (0..63)

  // ---- stage tables + p-rows
  sFE[t] = fE[t]; sFE[t + 256] = fE[t + 256];
  sFD[t] = fD[t]; sFD[t + 256] = fD[t + 256];
  {
    const float4 peT = pe[t];
    const float* xr = X + (size_t)b * SINQ * 3 + 3 * t;
    sEP[t] = make_float4(xr[0] + peT.x, xr[1] + peT.y, xr[2] + peT.z, 1.f);
    if (t < SPRQ) {
      const float* tr = T + (size_t)b * SPRQ * 3 + 3 * t;
      sDP[t] = make_float4(tr[0] + peT.x, tr[1] + peT.y, tr[2] + peT.z, 1.f);
    }
  }
  __syncthreads();

  const f2 z2 = mkf2(0.f, 0.f);

  // ================= ENCODER =================
  f2 qa2[4], qb2[4];
#pragma unroll
  for (int m = 0; m < 4; ++m) {
    const float4 pr = sEP[g + 64 * m];
    const float q0 = (einw[0] * pr.x + einw[1] * pr.y + einw[2] * pr.z + einb[0]) * QS;
    const float q1 = (einw[3] * pr.x + einw[4] * pr.y + einw[5] * pr.z + einb[1]) * QS;
    const float q2 = (einw[6] * pr.x + einw[7] * pr.y + einw[8] * pr.z + einb[2]) * QS;
    qa2[m] = mkf2(q0 * einw[9]  + q1 * einw[12] + q2 * einw[15],
                  q0 * einw[10] + q1 * einw[13] + q2 * einw[16]);
    qb2[m] = mkf2(q0 * einw[11] + q1 * einw[14] + q2 * einw[17],
                  q0 * einb[3]  + q1 * einb[4]  + q2 * einb[5]);
  }
  const int rho = g + 64 * s;
  float pr0, pr1, pr2;
  { const float4 prw = sEP[rho]; pr0 = prw.x; pr1 = prw.y; pr2 = prw.z; }

  // attention: slot s handles j = 4*jj+s; 4 rows share each streamed p_j
  f2 ac01[4] = {z2, z2, z2, z2}, ac23[4] = {z2, z2, z2, z2};
#pragma unroll 4
  for (int jj = 0; jj < 64; ++jj) {
    const float4 P = sEP[4 * jj + s];
    const f2 p01 = mkf2(P.x, P.y), p23 = mkf2(P.z, P.w);
#pragma unroll
    for (int m = 0; m < 4; ++m) {
      const f2 sc2 = fma2(p01, qa2[m], p23 * qb2[m]);
      const float e = EXP2(sc2.x + sc2.y);
      const f2 ee = mkf2(e, e);
      ac01[m] = fma2(ee, p01, ac01[m]);
      ac23[m] = fma2(ee, p23, ac23[m]);   // .y accumulates denominator
    }
  }
#pragma unroll
  for (int m = 0; m < 4; ++m) { C4F2(ac01[m]); C4F2(ac23[m]); }

  float r0, r1, r2;
  {
    const float myd  = sel4(ac23[0].y, ac23[1].y, ac23[2].y, ac23[3].y, s);
    const float mya0 = sel4(ac01[0].x, ac01[1].x, ac01[2].x, ac01[3].x, s);
    const float mya1 = sel4(ac01[0].y, ac01[1].y, ac01[2].y, ac01[3].y, s);
    const float mya2 = sel4(ac23[0].x, ac23[1].x, ac23[2].x, ac23[3].x, s);
    const float rdn = 1.f / myd;
    const float u0 = mya0 * rdn, u1 = mya1 * rdn, u2 = mya2 * rdn;
    const float v0 = einw[18] * u0 + einw[19] * u1 + einw[20] * u2 + einb[6];
    const float v1 = einw[21] * u0 + einw[22] * u1 + einw[23] * u2 + einb[7];
    const float v2 = einw[24] * u0 + einw[25] * u1 + einw[26] * u2 + einb[8];
    r0 = eow[0] * v0 + eow[1] * v1 + eow[2] * v2 + eob[0] + pr0;
    r1 = eow[3] * v0 + eow[4] * v1 + eow[5] * v2 + eob[1] + pr1;
    r2 = eow[6] * v0 + eow[7] * v1 + eow[8] * v2 + eob[2] + pr2;
  }
  float mean, rstd;
  block_stats(r0 + r1 + r2, r0 * r0 + r1 * r1 + r2 * r2, sRed, t, 768.f, mean, rstd);
  const int lie = rho * 3;
  const float x20 = (r0 - mean) * rstd * eln1w[lie + 0] + eln1b[lie + 0];
  const float x21 = (r1 - mean) * rstd * eln1w[lie + 1] + eln1b[lie + 1];
  const float x22 = (r2 - mean) * rstd * eln1w[lie + 2] + eln1b[lie + 2];

  // FFN: slot s handles pairs pp = 4*jj+s over 4 gathered rows
  unsigned xxm[4], xym[4], xzm[4];
  {
    const unsigned xx = pk16(x20, x20), xy = pk16(x21, x21), xz = pk16(x22, x22);
    const int base = lane & ~3;
#pragma unroll
    for (int m = 0; m < 4; ++m) {
      xxm[m] = (unsigned)__shfl((int)xx, base + m, 64);
      xym[m] = (unsigned)__shfl((int)xy, base + m, 64);
      xzm[m] = (unsigned)__shfl((int)xz, base + m, 64);
    }
  }
  float c0[4] = {0, 0, 0, 0}, c1[4] = {0, 0, 0, 0}, c2[4] = {0, 0, 0, 0};
#pragma unroll 4
  for (int jj = 0; jj < 64; ++jj) {
    const int pp = 4 * jj + s;
    const uint4 A = sFE[2 * pp];
    const uint4 B = sFE[2 * pp + 1];
    const h2 w1x = uph(A.x), w1y = uph(A.y), w1z = uph(A.z), b1h = uph(A.w);
    const h2 w2x = uph(B.x), w2y = uph(B.y), w2z = uph(B.z);
#pragma unroll
    for (int m = 0; m < 4; ++m) {
      h2 z = w1z * uph(xzm[m]) + b1h;
      z = w1y * uph(xym[m]) + z;
      z = w1x * uph(xxm[m]) + z;
      z = relu2(z);
      c0[m] = FDOT2(z, w2x, c0[m]);
      c1[m] = FDOT2(z, w2y, c1[m]);
      c2[m] = FDOT2(z, w2z, c2[m]);
    }
  }
#pragma unroll
  for (int m = 0; m < 4; ++m) { C4S(c0[m]); C4S(c1[m]); C4S(c2[m]); }

  const float h0 = sel4(c0[0], c0[1], c0[2], c0[3], s) + eb2[0] + x20;
  const float h1 = sel4(c1[0], c1[1], c1[2], c1[3], s) + eb2[1] + x21;
  const float h2v = sel4(c2[0], c2[1], c2[2], c2[3], s) + eb2[2] + x22;
  block_stats(h0 + h1 + h2v, h0 * h0 + h1 * h1 + h2v * h2v, sRed, t, 768.f, mean, rstd);
  {
    const float e0 = (h0 - mean) * rstd * eln2w[lie + 0] + eln2b[lie + 0];
    const float e1 = (h1 - mean) * rstd * eln2w[lie + 1] + eln2b[lie + 1];
    const float e2 = (h2v - mean) * rstd * eln2w[lie + 2] + eln2b[lie + 2];
    sCE[rho] = make_float4(e0, e1, e2, 1.f);
  }
  __syncthreads();

  // ================= DECODER =================
  const int ms = s & 1;            // assigned row: ra = g + 64*ms
  const int ra = g + 64 * ms;

  f2 dqa2[2], dqb2[2];
#pragma unroll
  for (int m = 0; m < 2; ++m) {
    const float4 pr = sDP[g + 64 * m];
    const float q0 = (a1w[0] * pr.x + a1w[1] * pr.y + a1w[2] * pr.z + a1b[0]) * QS;
    const float q1 = (a1w[3] * pr.x + a1w[4] * pr.y + a1w[5] * pr.z + a1b[1]) * QS;
    const float q2 = (a1w[6] * pr.x + a1w[7] * pr.y + a1w[8] * pr.z + a1b[2]) * QS;
    dqa2[m] = mkf2(q0 * a1w[9]  + q1 * a1w[12] + q2 * a1w[15],
                   q0 * a1w[10] + q1 * a1w[13] + q2 * a1w[16]);
    dqb2[m] = mkf2(q0 * a1w[11] + q1 * a1w[14] + q2 * a1w[17],
                   q0 * a1b[3]  + q1 * a1b[4]  + q2 * a1b[5]);
  }
  float pt0, pt1, pt2;
  { const float4 prw = sDP[ra]; pt0 = prw.x; pt1 = prw.y; pt2 = prw.z; }

  // self-attn (additive tril(ones) mask -> +LOG2E seed when j<=row)
  f2 dc01[2] = {z2, z2}, dc23[2] = {z2, z2};
#pragma unroll 2
  for (int jj = 0; jj < 32; ++jj) {
    const int j = 4 * jj + s;
    const float4 P = sDP[j];
    const f2 p01 = mkf2(P.x, P.y), p23 = mkf2(P.z, P.w);
#pragma unroll
    for (int m = 0; m < 2; ++m) {
      const float seed = (j <= g + 64 * m) ? LOG2E : 0.f;
      const f2 sc2 = fma2(p01, dqa2[m], p23 * dqb2[m]);
      const float e = EXP2(sc2.x + sc2.y + seed);
      const f2 ee = mkf2(e, e);
      dc01[m] = fma2(ee, p01, dc01[m]);
      dc23[m] = fma2(ee, p23, dc23[m]);
    }
  }
#pragma unroll
  for (int m = 0; m < 2; ++m) { C4F2(dc01[m]); C4F2(dc23[m]); }
  {
    const float myd = sel2(dc23[0].y, dc23[1].y, ms);
    const float rdn = 1.f / myd;
    const float u0 = sel2(dc01[0].x, dc01[1].x, ms) * rdn;
    const float u1 = sel2(dc01[0].y, dc01[1].y, ms) * rdn;
    const float u2 = sel2(dc23[0].x, dc23[1].x, ms) * rdn;
    const float v0 = a1w[18] * u0 + a1w[19] * u1 + a1w[20] * u2 + a1b[6];
    const float v1 = a1w[21] * u0 + a1w[22] * u1 + a1w[23] * u2 + a1b[7];
    const float v2 = a1w[24] * u0 + a1w[25] * u1 + a1w[26] * u2 + a1b[8];
    r0 = a1ow[0] * v0 + a1ow[1] * v1 + a1ow[2] * v2 + a1ob[0] + pt0;
    r1 = a1ow[3] * v0 + a1ow[4] * v1 + a1ow[5] * v2 + a1ob[1] + pt1;
    r2 = a1ow[6] * v0 + a1ow[7] * v1 + a1ow[8] * v2 + a1ob[2] + pt2;
  }
  const int contrib = (s < 2) ? 1 : 0;
  block_stats(contrib ? r0 + r1 + r2 : 0.f,
              contrib ? r0 * r0 + r1 * r1 + r2 * r2 : 0.f, sRed, t, 384.f, mean, rstd);
  const int lid = ra * 3;
  const float dl1w0 = dln1w[lid + 0], dl1w1 = dln1w[lid + 1], dl1w2 = dln1w[lid + 2];
  const float dl1b0 = dln1b[lid + 0], dl1b1 = dln1b[lid + 1], dl1b2 = dln1b[lid + 2];
  const float x2d0 = (r0 - mean) * rstd * dl1w0 + dl1b0;
  const float x2d1 = (r1 - mean) * rstd * dl1w1 + dl1b1;
  const float x2d2 = (r2 - mean) * rstd * dl1w2 + dl1b2;

  // cross-attn queries for BOTH rows (shfl + selects; no dynamic stores)
  f2 cqa2[2], cqb2[2];
  {
    const int oth = (lane & ~3) + (ms ^ 1);
    const float ox0 = __shfl(x2d0, oth, 64);
    const float ox1 = __shfl(x2d1, oth, 64);
    const float ox2 = __shfl(x2d2, oth, 64);
    const float y00 = ms ? ox0 : x2d0;   // row m=0
    const float y01 = ms ? ox1 : x2d1;
    const float y02 = ms ? ox2 : x2d2;
    const float y10 = ms ? x2d0 : ox0;   // row m=1
    const float y11 = ms ? x2d1 : ox1;
    const float y12 = ms ? x2d2 : ox2;
#pragma unroll
    for (int m = 0; m < 2; ++m) {
      const float y0 = m ? y10 : y00, y1 = m ? y11 : y01, y2 = m ? y12 : y02;
      const float q0 = (a2w[0] * y0 + a2w[1] * y1 + a2w[2] * y2 + a2b[0]) * QS;
      const float q1 = (a2w[3] * y0 + a2w[4] * y1 + a2w[5] * y2 + a2b[1]) * QS;
      const float q2 = (a2w[6] * y0 + a2w[7] * y1 + a2w[8] * y2 + a2b[2]) * QS;
      cqa2[m] = mkf2(q0 * a2w[9]  + q1 * a2w[12] + q2 * a2w[15],
                     q0 * a2w[10] + q1 * a2w[13] + q2 * a2w[16]);
      cqb2[m] = mkf2(q0 * a2w[11] + q1 * a2w[14] + q2 * a2w[17],
                     q0 * a2b[3]  + q1 * a2b[4]  + q2 * a2b[5]);
    }
  }
  dc01[0] = z2; dc01[1] = z2; dc23[0] = z2; dc23[1] = z2;
#pragma unroll 4
  for (int jj = 0; jj < 64; ++jj) {
    const float4 P = sCE[4 * jj + s];
    const f2 p01 = mkf2(P.x, P.y), p23 = mkf2(P.z, P.w);
#pragma unroll
    for (int m = 0; m < 2; ++m) {
      const f2 sc2 = fma2(p01, cqa2[m], p23 * cqb2[m]);
      const float e = EXP2(sc2.x + sc2.y);
      const f2 ee = mkf2(e, e);
      dc01[m] = fma2(ee, p01, dc01[m]);
      dc23[m] = fma2(ee, p23, dc23[m]);
    }
  }
#pragma unroll
  for (int m = 0; m < 2; ++m) { C4F2(dc01[m]); C4F2(dc23[m]); }
  {
    const float myd = sel2(dc23[0].y, dc23[1].y, ms);
    const float rdn = 1.f / myd;
    const float u0 = sel2(dc01[0].x, dc01[1].x, ms) * rdn;
    const float u1 = sel2(dc01[0].y, dc01[1].y, ms) * rdn;
    const float u2 = sel2(dc23[0].x, dc23[1].x, ms) * rdn;
    const float v0 = a2w[18] * u0 + a2w[19] * u1 + a2w[20] * u2 + a2b[6];
    const float v1 = a2w[21] * u0 + a2w[22] * u1 + a2w[23] * u2 + a2b[7];
    const float v2 = a2w[24] * u0 + a2w[25] * u1 + a2w[26] * u2 + a2b[8];
    r0 = a2ow[0] * v0 + a2ow[1] * v1 + a2ow[2] * v2 + a2ob[0] + x2d0;
    r1 = a2ow[3] * v0 + a2ow[4] * v1 + a2ow[5] * v2 + a2ob[1] + x2d1;
    r2 = a2ow[6] * v0 + a2ow[7] * v1 + a2ow[8] * v2 + a2ob[2] + x2d2;
  }
  block_stats(contrib ? r0 + r1 + r2 : 0.f,
              contrib ? r0 * r0 + r1 * r1 + r2 * r2 : 0.f, sRed, t, 384.f, mean, rstd);
  const float x30 = (r0 - mean) * rstd * dl1w0 + dl1b0;   // dec_ln1 AGAIN
  const float x31 = (r1 - mean) * rstd * dl1w1 + dl1b1;
  const float x32 = (r2 - mean) * rstd * dl1w2 + dl1b2;

  // dec FFN: both rows' x3 as h2 broadcasts (shfl + selects)
  unsigned x3x0, x3y0, x3z0, x3x1, x3y1, x3z1;
  {
    const unsigned xx = pk16(x30, x30), xy = pk16(x31, x31), xz = pk16(x32, x32);
    const int oth = (lane & ~3) + (ms ^ 1);
    const unsigned oxx = (unsigned)__shfl((int)xx, oth, 64);
    const unsigned oxy = (unsigned)__shfl((int)xy, oth, 64);
    const unsigned oxz = (unsigned)__shfl((int)xz, oth, 64);
    x3x0 = ms ? oxx : xx; x3y0 = ms ? oxy : xy; x3z0 = ms ? oxz : xz;
    x3x1 = ms ? xx : oxx; x3y1 = ms ? xy : oxy; x3z1 = ms ? xz : oxz;
  }
  float e0[2] = {0, 0}, e1[2] = {0, 0}, e2[2] = {0, 0};
#pragma unroll 4
  for (int jj = 0; jj < 64; ++jj) {
    const int pp = 4 * jj + s;
    const uint4 A = sFD[2 * pp];
    const uint4 B = sFD[2 * pp + 1];
    const h2 w1x = uph(A.x), w1y = uph(A.y), w1z = uph(A.z), b1h = uph(A.w);
    const h2 w2x = uph(B.x), w2y = uph(B.y), w2z = uph(B.z);
#pragma unroll
    for (int m = 0; m < 2; ++m) {
      h2 z = w1z * uph(m ? x3z1 : x3z0) + b1h;
      z = w1y * uph(m ? x3y1 : x3y0) + z;
      z = w1x * uph(m ? x3x1 : x3x0) + z;
      z = relu2(z);
      e0[m] = FDOT2(z, w2x, e0[m]);
      e1[m] = FDOT2(z, w2y, e1[m]);
      e2[m] = FDOT2(z, w2z, e2[m]);
    }
  }
#pragma unroll
  for (int m = 0; m < 2; ++m) { C4S(e0[m]); C4S(e1[m]); C4S(e2[m]); }

  const float f0 = sel2(e0[0], e0[1], ms) + db2[0] + x30;
  const float f1 = sel2(e1[0], e1[1], ms) + db2[1] + x31;
  const float f2v = sel2(e2[0], e2[1], ms) + db2[2] + x32;
  block_stats(contrib ? f0 + f1 + f2v : 0.f,
              contrib ? f0 * f0 + f1 * f1 + f2v * f2v : 0.f, sRed, t, 384.f, mean, rstd);
  if (s < 2) {
    float* op = out + ((size_t)b * SPRQ + ra) * 3;
    op[0] = (f0 - mean) * rstd * dln3w[lid + 0] + dln3b[lid + 0];
    op[1] = (f1 - mean) * rstd * dln3w[lid + 1] + dln3b[lid + 1];
    op[2] = (f2v - mean) * rstd * dln3w[lid + 2] + dln3b[lid + 2];
  }
}

extern "C" void kernel_launch(void* const* d_in, const int* in_sizes, int n_in,
                              void* d_out, int out_size, void* d_ws, size_t ws_size,
                              hipStream_t stream) {
  (void)in_sizes; (void)n_in; (void)out_size; (void)ws_size;
  float* ws = (float*)d_ws;
  uint4* fE = (uint4*)ws;                    // 8 KB
  uint4* fD = (uint4*)(ws + 2048);           // 8 KB
  float4* pe = (float4*)(ws + 4096);         // 4 KB

  pack_tabs<<<1, 256, 0, stream>>>(
      (const float*)d_in[8],  (const float*)d_in[9],  (const float*)d_in[10],
      (const float*)d_in[24], (const float*)d_in[25], (const float*)d_in[26],
      fE, fD, pe);

  fused_fwd<<<NB, 256, 0, stream>>>(
      (const float*)d_in[0],  (const float*)d_in[1],
      (const float*)d_in[2],  (const float*)d_in[3],
      (const float*)d_in[4],  (const float*)d_in[5],
      (const float*)d_in[6],  (const float*)d_in[7],
      (const float*)d_in[11],
      (const float*)d_in[12], (const float*)d_in[13],
      (const float*)d_in[14], (const float*)d_in[15],
      (const float*)d_in[16], (const float*)d_in[17],
      (const float*)d_in[18], (const float*)d_in[19],
      (const float*)d_in[20], (const float*)d_in[21],
      (const float*)d_in[22], (const float*)d_in[23],
      (const float*)d_in[27],
      (const float*)d_in[28], (const float*)d_in[29],
      fE, fD, pe,
      (float*)d_out);
}

// Round 4
// 173.695 us; speedup vs baseline: 1.0183x; 1.0128x over previous
//
#include <hip/hip_runtime.h>

#define NB   1024
#define SINQ 256
#define SPRQ 128
#define HIDQ 512

// pos_enc: emb[:, :3] = sin(pos * inv_freq[c]); inv_freq[c] = 10000^(-2c/256)
#define PEF1  0.93057207f
#define PEF2  0.86596438f
#define LOG2E 1.44269504089f
// q pre-scale: 1/sqrt(3) * log2(e)
#define QS    0.83298066476f

typedef _Float16 h2 __attribute__((ext_vector_type(2)));
typedef float    f2 __attribute__((ext_vector_type(2)));

#if defined(__has_builtin) && __has_builtin(__builtin_amdgcn_exp2f)
#define EXP2(x) __builtin_amdgcn_exp2f(x)
#else
#define EXP2(x) exp2f(x)
#endif

#if defined(__has_builtin) && __has_builtin(__builtin_amdgcn_fdot2)
#define FDOT2(a, b, c) __builtin_amdgcn_fdot2((a), (b), (c), false)
#else
__device__ __forceinline__ float fdot2_sw(h2 a, h2 b, float c) {
  return fmaf((float)a.x, (float)b.x, fmaf((float)a.y, (float)b.y, c));
}
#define FDOT2(a, b, c) fdot2_sw((a), (b), (c))
#endif

__device__ __forceinline__ unsigned pk16(float a, float b) {
  h2 v; v.x = (_Float16)a; v.y = (_Float16)b;
  return __builtin_bit_cast(unsigned, v);
}
__device__ __forceinline__ h2 uph(unsigned u) { return __builtin_bit_cast(h2, u); }

__device__ __forceinline__ h2 relu2(h2 z) {
#if defined(__has_builtin) && __has_builtin(__builtin_elementwise_max)
  h2 zz; zz.x = (_Float16)0.f; zz.y = (_Float16)0.f;
  return __builtin_elementwise_max(z, zz);
#else
  z.x = z.x > (_Float16)0.f ? z.x : (_Float16)0.f;
  z.y = z.y > (_Float16)0.f ? z.y : (_Float16)0.f;
  return z;
#endif
}

__device__ __forceinline__ f2 mkf2(float a, float b) { f2 r; r.x = a; r.y = b; return r; }
__device__ __forceinline__ f2 spl(float a) { f2 r; r.x = a; r.y = a; return r; }
#if defined(__has_builtin) && __has_builtin(__builtin_elementwise_fma)
__device__ __forceinline__ f2 fma2(f2 a, f2 b, f2 c) {
  return __builtin_elementwise_fma(a, b, c);   // v_pk_fma_f32
}
#else
__device__ __forceinline__ f2 fma2(f2 a, f2 b, f2 c) {
  f2 r; r.x = fmaf(a.x, b.x, c.x); r.y = fmaf(a.y, b.y, c.y); return r;
}
#endif

// xor-combine over the 4 slot lanes of a quad.
// NOTE: R1 post-mortem — DPP versions broke correctness; keep __shfl_xor.
#define C4S(v)  { (v) += __shfl_xor((v), 1, 64); (v) += __shfl_xor((v), 2, 64); }

// register-only selects (v_cndmask chains) -- NEVER index private arrays
// with a runtime value: that demotes them to scratch (HBM!).
__device__ __forceinline__ float sel4(float a, float b, float c, float d, int s) {
  float r = a;
  r = (s == 1) ? b : r;
  r = (s == 2) ? c : r;
  r = (s == 3) ? d : r;
  return r;
}
__device__ __forceinline__ float sel2(float a, float b, int s) {
  return s ? b : a;
}

// Block-wide (256 thr) mean/rstd over nelem values. One barrier per call:
// each call gets its own sRed slot (rotation removes the WAR pre-barrier).
__device__ __forceinline__ void block_stats(float s1, float s2, float* slot,
                                            int tid, float nelem,
                                            float& mean, float& rstd) {
#pragma unroll
  for (int off = 32; off > 0; off >>= 1) {
    s1 += __shfl_xor(s1, off, 64);
    s2 += __shfl_xor(s2, off, 64);
  }
  if ((tid & 63) == 0) {
    slot[((tid >> 6) << 1) + 0] = s1;
    slot[((tid >> 6) << 1) + 1] = s2;
  }
  __syncthreads();
  float t1 = slot[0] + slot[2] + slot[4] + slot[6];
  float t2 = slot[1] + slot[3] + slot[5] + slot[7];
  mean = t1 / nelem;
  rstd = rsqrtf(t2 / nelem - mean * mean + 1e-5f);
}

// Pack f16 FFN pair-records and the sin() table.
__global__ __launch_bounds__(256) void pack_tabs(
    const float* __restrict__ ew1, const float* __restrict__ eb1,
    const float* __restrict__ ew2,
    const float* __restrict__ dw1, const float* __restrict__ db1,
    const float* __restrict__ dw2,
    uint4* __restrict__ fE, uint4* __restrict__ fD, float4* __restrict__ pe)
{
  const int t = threadIdx.x;        // pair index, 0..255
  const int k0 = 2 * t, k1 = 2 * t + 1;
  fE[2 * t] = make_uint4(pk16(ew1[3 * k0], ew1[3 * k1]),
                         pk16(ew1[3 * k0 + 1], ew1[3 * k1 + 1]),
                         pk16(ew1[3 * k0 + 2], ew1[3 * k1 + 2]),
                         pk16(eb1[k0], eb1[k1]));
  fE[2 * t + 1] = make_uint4(pk16(ew2[k0], ew2[k1]),
                             pk16(ew2[HIDQ + k0], ew2[HIDQ + k1]),
                             pk16(ew2[2 * HIDQ + k0], ew2[2 * HIDQ + k1]), 0u);
  fD[2 * t] = make_uint4(pk16(dw1[3 * k0], dw1[3 * k1]),
                         pk16(dw1[3 * k0 + 1], dw1[3 * k1 + 1]),
                         pk16(dw1[3 * k0 + 2], dw1[3 * k1 + 2]),
                         pk16(db1[k0], db1[k1]));
  fD[2 * t + 1] = make_uint4(pk16(dw2[k0], dw2[k1]),
                             pk16(dw2[HIDQ + k0], dw2[HIDQ + k1]),
                             pk16(dw2[2 * HIDQ + k0], dw2[2 * HIDQ + k1]), 0u);
  const float p = (float)t;
  pe[t] = make_float4(sinf(p), sinf(p * PEF1), sinf(p * PEF2), 0.f);
}

// One 256-thr block per batch element. 4-way slot-split (s = t&3) over
// key-QUADS: transposed LDS stores component c of 4 consecutive keys as one
// float4, so scores for 4 keys = 6 pk_fma, accumulate = 6 pk_fma + 2 pk_add
// (14 VALU + 4 exp per 4 keys vs 24 + 4 in the row-major form).
__global__ __launch_bounds__(256, 4) void fused_fwd(
    const float* __restrict__ X, const float* __restrict__ T,
    const float* __restrict__ einw, const float* __restrict__ einb,
    const float* __restrict__ eow,  const float* __restrict__ eob,
    const float* __restrict__ eln1w, const float* __restrict__ eln1b,
    const float* __restrict__ eb2,
    const float* __restrict__ eln2w, const float* __restrict__ eln2b,
    const float* __restrict__ a1w, const float* __restrict__ a1b,
    const float* __restrict__ a1ow, const float* __restrict__ a1ob,
    const float* __restrict__ dln1w, const float* __restrict__ dln1b,
    const float* __restrict__ a2w, const float* __restrict__ a2b,
    const float* __restrict__ a2ow, const float* __restrict__ a2ob,
    const float* __restrict__ db2,
    const float* __restrict__ dln3w, const float* __restrict__ dln3b,
    const uint4* __restrict__ fE, const uint4* __restrict__ fD,
    const float4* __restrict__ pe,
    float* __restrict__ out)
{
  __shared__ uint4  sFE[2 * 256];                       // 8 KB enc FFN
  __shared__ uint4  sFD[2 * 256];                       // 8 KB dec FFN
  __shared__ float4 sEP[SINQ];                          // 4 KB p_X rows
  __shared__ float4 sDP[SPRQ];                          // 2 KB p_T rows
  __shared__ __align__(16) float sEPq[(SINQ / 4) * 12]; // 3 KB p_X quad-T
  __shared__ __align__(16) float sDPq[(SPRQ / 4) * 12]; // 1.5 KB p_T quad-T
  __shared__ __align__(16) float sCEq[(SINQ / 4) * 12]; // 3 KB enc_out quad-T
  __shared__ float  sRed[5 * 8];                        // per-call slots

  const int b = blockIdx.x;
  const int t = threadIdx.x;
  const int lane = t & 63;
  const int s = t & 3;             // slot
  const int g = t >> 2;            // enc row-group (0..63)

  // ---- stage tables + p-rows (row-major AND quad-transposed)
  sFE[t] = fE[t]; sFE[t + 256] = fE[t + 256];
  sFD[t] = fD[t]; sFD[t + 256] = fD[t + 256];
  {
    const float4 peT = pe[t];
    const float* xr = X + (size_t)b * SINQ * 3 + 3 * t;
    const float p0 = xr[0] + peT.x, p1 = xr[1] + peT.y, p2 = xr[2] + peT.z;
    sEP[t] = make_float4(p0, p1, p2, 1.f);
    const int q = t >> 2, sl = t & 3;
    sEPq[(q * 3 + 0) * 4 + sl] = p0;
    sEPq[(q * 3 + 1) * 4 + sl] = p1;
    sEPq[(q * 3 + 2) * 4 + sl] = p2;
    if (t < SPRQ) {
      const float* tr = T + (size_t)b * SPRQ * 3 + 3 * t;
      const float d0 = tr[0] + peT.x, d1 = tr[1] + peT.y, d2 = tr[2] + peT.z;
      sDP[t] = make_float4(d0, d1, d2, 1.f);
      sDPq[(q * 3 + 0) * 4 + sl] = d0;
      sDPq[(q * 3 + 1) * 4 + sl] = d1;
      sDPq[(q * 3 + 2) * 4 + sl] = d2;
    }
  }
  __syncthreads();

  const f2 z2 = mkf2(0.f, 0.f);
  float r0, r1, r2;
  float mean, rstd;

  // ================= ENCODER =================
  f2 qa2[4], qb2[4];
#pragma unroll
  for (int m = 0; m < 4; ++m) {
    const float4 pr = sEP[g + 64 * m];
    const float q0 = (einw[0] * pr.x + einw[1] * pr.y + einw[2] * pr.z + einb[0]) * QS;
    const float q1 = (einw[3] * pr.x + einw[4] * pr.y + einw[5] * pr.z + einb[1]) * QS;
    const float q2 = (einw[6] * pr.x + einw[7] * pr.y + einw[8] * pr.z + einb[2]) * QS;
    qa2[m] = mkf2(q0 * einw[9]  + q1 * einw[12] + q2 * einw[15],
                  q0 * einw[10] + q1 * einw[13] + q2 * einw[16]);
    qb2[m] = mkf2(q0 * einw[11] + q1 * einw[14] + q2 * einw[17],
                  q0 * einb[3]  + q1 * einb[4]  + q2 * einb[5]);
  }
  const int rho = g + 64 * s;
  float pr0, pr1, pr2;
  { const float4 prw = sEP[rho]; pr0 = prw.x; pr1 = prw.y; pr2 = prw.z; }

  // attention: slot s handles key-quads qid = 4*u+s (4 keys each)
  f2 a0p[4], a1p[4], a2p[4], dnp[4];
#pragma unroll
  for (int m = 0; m < 4; ++m) { a0p[m] = z2; a1p[m] = z2; a2p[m] = z2; dnp[m] = z2; }
#pragma unroll 2
  for (int u = 0; u < 16; ++u) {
    const int qid = 4 * u + s;
    const float4 P0 = *(const float4*)&sEPq[(qid * 3 + 0) * 4];
    const float4 P1 = *(const float4*)&sEPq[(qid * 3 + 1) * 4];
    const float4 P2 = *(const float4*)&sEPq[(qid * 3 + 2) * 4];
    const f2 p0l = mkf2(P0.x, P0.y), p0h = mkf2(P0.z, P0.w);
    const f2 p1l = mkf2(P1.x, P1.y), p1h = mkf2(P1.z, P1.w);
    const f2 p2l = mkf2(P2.x, P2.y), p2h = mkf2(P2.z, P2.w);
#pragma unroll
    for (int m = 0; m < 4; ++m) {
      const f2 qx = spl(qa2[m].x), qy = spl(qa2[m].y);
      const f2 qz = spl(qb2[m].x), qc = spl(qb2[m].y);
      const f2 sl = fma2(p0l, qx, fma2(p1l, qy, fma2(p2l, qz, qc)));
      const f2 sh = fma2(p0h, qx, fma2(p1h, qy, fma2(p2h, qz, qc)));
      const f2 el = mkf2(EXP2(sl.x), EXP2(sl.y));
      const f2 eh = mkf2(EXP2(sh.x), EXP2(sh.y));
      dnp[m] = dnp[m] + el + eh;
      a0p[m] = fma2(el, p0l, fma2(eh, p0h, a0p[m]));
      a1p[m] = fma2(el, p1l, fma2(eh, p1h, a1p[m]));
      a2p[m] = fma2(el, p2l, fma2(eh, p2h, a2p[m]));
    }
  }
  float aa0[4], aa1[4], aa2[4], adn[4];
#pragma unroll
  for (int m = 0; m < 4; ++m) {
    aa0[m] = a0p[m].x + a0p[m].y; C4S(aa0[m]);
    aa1[m] = a1p[m].x + a1p[m].y; C4S(aa1[m]);
    aa2[m] = a2p[m].x + a2p[m].y; C4S(aa2[m]);
    adn[m] = dnp[m].x + dnp[m].y; C4S(adn[m]);
  }

  {
    const float myd  = sel4(adn[0], adn[1], adn[2], adn[3], s);
    const float mya0 = sel4(aa0[0], aa0[1], aa0[2], aa0[3], s);
    const float mya1 = sel4(aa1[0], aa1[1], aa1[2], aa1[3], s);
    const float mya2 = sel4(aa2[0], aa2[1], aa2[2], aa2[3], s);
    const float rdn = 1.f / myd;
    const float u0 = mya0 * rdn, u1 = mya1 * rdn, u2 = mya2 * rdn;
    const float v0 = einw[18] * u0 + einw[19] * u1 + einw[20] * u2 + einb[6];
    const float v1 = einw[21] * u0 + einw[22] * u1 + einw[23] * u2 + einb[7];
    const float v2 = einw[24] * u0 + einw[25] * u1 + einw[26] * u2 + einb[8];
    r0 = eow[0] * v0 + eow[1] * v1 + eow[2] * v2 + eob[0] + pr0;
    r1 = eow[3] * v0 + eow[4] * v1 + eow[5] * v2 + eob[1] + pr1;
    r2 = eow[6] * v0 + eow[7] * v1 + eow[8] * v2 + eob[2] + pr2;
  }
  block_stats(r0 + r1 + r2, r0 * r0 + r1 * r1 + r2 * r2, sRed + 0, t, 768.f, mean, rstd);
  const int lie = rho * 3;
  const float x20 = (r0 - mean) * rstd * eln1w[lie + 0] + eln1b[lie + 0];
  const float x21 = (r1 - mean) * rstd * eln1w[lie + 1] + eln1b[lie + 1];
  const float x22 = (r2 - mean) * rstd * eln1w[lie + 2] + eln1b[lie + 2];

  // FFN: slot s handles pairs pp = 4*jj+s over 4 gathered rows
  unsigned xxm[4], xym[4], xzm[4];
  {
    const unsigned xx = pk16(x20, x20), xy = pk16(x21, x21), xz = pk16(x22, x22);
    const int base = lane & ~3;
#pragma unroll
    for (int m = 0; m < 4; ++m) {
      xxm[m] = (unsigned)__shfl((int)xx, base + m, 64);
      xym[m] = (unsigned)__shfl((int)xy, base + m, 64);
      xzm[m] = (unsigned)__shfl((int)xz, base + m, 64);
    }
  }
  float c0[4] = {0, 0, 0, 0}, c1[4] = {0, 0, 0, 0}, c2[4] = {0, 0, 0, 0};
#pragma unroll 4
  for (int jj = 0; jj < 64; ++jj) {
    const int pp = 4 * jj + s;
    const uint4 A = sFE[2 * pp];
    const uint4 B = sFE[2 * pp + 1];
    const h2 w1x = uph(A.x), w1y = uph(A.y), w1z = uph(A.z), b1h = uph(A.w);
    const h2 w2x = uph(B.x), w2y = uph(B.y), w2z = uph(B.z);
#pragma unroll
    for (int m = 0; m < 4; ++m) {
      h2 z = w1z * uph(xzm[m]) + b1h;
      z = w1y * uph(xym[m]) + z;
      z = w1x * uph(xxm[m]) + z;
      z = relu2(z);
      c0[m] = FDOT2(z, w2x, c0[m]);
      c1[m] = FDOT2(z, w2y, c1[m]);
      c2[m] = FDOT2(z, w2z, c2[m]);
    }
  }
#pragma unroll
  for (int m = 0; m < 4; ++m) { C4S(c0[m]); C4S(c1[m]); C4S(c2[m]); }

  const float h0 = sel4(c0[0], c0[1], c0[2], c0[3], s) + eb2[0] + x20;
  const float h1 = sel4(c1[0], c1[1], c1[2], c1[3], s) + eb2[1] + x21;
  const float h2v = sel4(c2[0], c2[1], c2[2], c2[3], s) + eb2[2] + x22;
  block_stats(h0 + h1 + h2v, h0 * h0 + h1 * h1 + h2v * h2v, sRed + 8, t, 768.f, mean, rstd);
  {
    const float e0 = (h0 - mean) * rstd * eln2w[lie + 0] + eln2b[lie + 0];
    const float e1 = (h1 - mean) * rstd * eln2w[lie + 1] + eln2b[lie + 1];
    const float e2 = (h2v - mean) * rstd * eln2w[lie + 2] + eln2b[lie + 2];
    const int q = rho >> 2, sl = rho & 3;
    sCEq[(q * 3 + 0) * 4 + sl] = e0;
    sCEq[(q * 3 + 1) * 4 + sl] = e1;
    sCEq[(q * 3 + 2) * 4 + sl] = e2;
  }
  __syncthreads();

  // ================= DECODER =================
  const int ms = s & 1;            // assigned row: ra = g + 64*ms
  const int ra = g + 64 * ms;

  f2 dqa2[2], dqb2[2];
#pragma unroll
  for (int m = 0; m < 2; ++m) {
    const float4 pr = sDP[g + 64 * m];
    const float q0 = (a1w[0] * pr.x + a1w[1] * pr.y + a1w[2] * pr.z + a1b[0]) * QS;
    const float q1 = (a1w[3] * pr.x + a1w[4] * pr.y + a1w[5] * pr.z + a1b[1]) * QS;
    const float q2 = (a1w[6] * pr.x + a1w[7] * pr.y + a1w[8] * pr.z + a1b[2]) * QS;
    dqa2[m] = mkf2(q0 * a1w[9]  + q1 * a1w[12] + q2 * a1w[15],
                   q0 * a1w[10] + q1 * a1w[13] + q2 * a1w[16]);
    dqb2[m] = mkf2(q0 * a1w[11] + q1 * a1w[14] + q2 * a1w[17],
                   q0 * a1b[3]  + q1 * a1b[4]  + q2 * a1b[5]);
  }
  float pt0, pt1, pt2;
  { const float4 prw = sDP[ra]; pt0 = prw.x; pt1 = prw.y; pt2 = prw.z; }

  // self-attn (additive tril(ones) mask -> +LOG2E seed when j<=row)
  f2 d0p[2], d1p[2], d2p[2], ddp[2];
#pragma unroll
  for (int m = 0; m < 2; ++m) { d0p[m] = z2; d1p[m] = z2; d2p[m] = z2; ddp[m] = z2; }
#pragma unroll 2
  for (int u = 0; u < 8; ++u) {
    const int qid = 4 * u + s;
    const int j0 = 4 * qid;
    const float4 P0 = *(const float4*)&sDPq[(qid * 3 + 0) * 4];
    const float4 P1 = *(const float4*)&sDPq[(qid * 3 + 1) * 4];
    const float4 P2 = *(const float4*)&sDPq[(qid * 3 + 2) * 4];
    const f2 p0l = mkf2(P0.x, P0.y), p0h = mkf2(P0.z, P0.w);
    const f2 p1l = mkf2(P1.x, P1.y), p1h = mkf2(P1.z, P1.w);
    const f2 p2l = mkf2(P2.x, P2.y), p2h = mkf2(P2.z, P2.w);
#pragma unroll
    for (int m = 0; m < 2; ++m) {
      const int row = g + 64 * m;
      const f2 qx = spl(dqa2[m].x), qy = spl(dqa2[m].y), qz = spl(dqb2[m].x);
      const f2 seedl = mkf2(dqb2[m].y + (j0 + 0 <= row ? LOG2E : 0.f),
                            dqb2[m].y + (j0 + 1 <= row ? LOG2E : 0.f));
      const f2 seedh = mkf2(dqb2[m].y + (j0 + 2 <= row ? LOG2E : 0.f),
                            dqb2[m].y + (j0 + 3 <= row ? LOG2E : 0.f));
      const f2 sl = fma2(p0l, qx, fma2(p1l, qy, fma2(p2l, qz, seedl)));
      const f2 sh = fma2(p0h, qx, fma2(p1h, qy, fma2(p2h, qz, seedh)));
      const f2 el = mkf2(EXP2(sl.x), EXP2(sl.y));
      const f2 eh = mkf2(EXP2(sh.x), EXP2(sh.y));
      ddp[m] = ddp[m] + el + eh;
      d0p[m] = fma2(el, p0l, fma2(eh, p0h, d0p[m]));
      d1p[m] = fma2(el, p1l, fma2(eh, p1h, d1p[m]));
      d2p[m] = fma2(el, p2l, fma2(eh, p2h, d2p[m]));
    }
  }
  float da0[2], da1[2], da2[2], ddn[2];
#pragma unroll
  for (int m = 0; m < 2; ++m) {
    da0[m] = d0p[m].x + d0p[m].y; C4S(da0[m]);
    da1[m] = d1p[m].x + d1p[m].y; C4S(da1[m]);
    da2[m] = d2p[m].x + d2p[m].y; C4S(da2[m]);
    ddn[m] = ddp[m].x + ddp[m].y; C4S(ddn[m]);
  }
  {
    const float myd = sel2(ddn[0], ddn[1], ms);
    const float rdn = 1.f / myd;
    const float u0 = sel2(da0[0], da0[1], ms) * rdn;
    const float u1 = sel2(da1[0], da1[1], ms) * rdn;
    const float u2 = sel2(da2[0], da2[1], ms) * rdn;
    const float v0 = a1w[18] * u0 + a1w[19] * u1 + a1w[20] * u2 + a1b[6];
    const float v1 = a1w[21] * u0 + a1w[22] * u1 + a1w[23] * u2 + a1b[7];
    const float v2 = a1w[24] * u0 + a1w[25] * u1 + a1w[26] * u2 + a1b[8];
    r0 = a1ow[0] * v0 + a1ow[1] * v1 + a1ow[2] * v2 + a1ob[0] + pt0;
    r1 = a1ow[3] * v0 + a1ow[4] * v1 + a1ow[5] * v2 + a1ob[1] + pt1;
    r2 = a1ow[6] * v0 + a1ow[7] * v1 + a1ow[8] * v2 + a1ob[2] + pt2;
  }
  const int contrib = (s < 2) ? 1 : 0;
  float mean2, rstd2;
  block_stats(contrib ? r0 + r1 + r2 : 0.f,
              contrib ? r0 * r0 + r1 * r1 + r2 * r2 : 0.f, sRed + 16, t, 384.f, mean2, rstd2);
  const int lid = ra * 3;
  const float dl1w0 = dln1w[lid + 0], dl1w1 = dln1w[lid + 1], dl1w2 = dln1w[lid + 2];
  const float dl1b0 = dln1b[lid + 0], dl1b1 = dln1b[lid + 1], dl1b2 = dln1b[lid + 2];
  const float x2d0 = (r0 - mean2) * rstd2 * dl1w0 + dl1b0;
  const float x2d1 = (r1 - mean2) * rstd2 * dl1w1 + dl1b1;
  const float x2d2 = (r2 - mean2) * rstd2 * dl1w2 + dl1b2;

  // cross-attn queries for BOTH rows (shfl + selects; no dynamic stores)
  f2 cqa2[2], cqb2[2];
  {
    const int oth = (lane & ~3) + (ms ^ 1);
    const float ox0 = __shfl(x2d0, oth, 64);
    const float ox1 = __shfl(x2d1, oth, 64);
    const float ox2 = __shfl(x2d2, oth, 64);
    const float y00 = ms ? ox0 : x2d0;   // row m=0
    const float y01 = ms ? ox1 : x2d1;
    const float y02 = ms ? ox2 : x2d2;
    const float y10 = ms ? x2d0 : ox0;   // row m=1
    const float y11 = ms ? x2d1 : ox1;
    const float y12 = ms ? x2d2 : ox2;
#pragma unroll
    for (int m = 0; m < 2; ++m) {
      const float y0 = m ? y10 : y00, y1 = m ? y11 : y01, y2 = m ? y12 : y02;
      const float q0 = (a2w[0] * y0 + a2w[1] * y1 + a2w[2] * y2 + a2b[0]) * QS;
      const float q1 = (a2w[3] * y0 + a2w[4] * y1 + a2w[5] * y2 + a2b[1]) * QS;
      const float q2 = (a2w[6] * y0 + a2w[7] * y1 + a2w[8] * y2 + a2b[2]) * QS;
      cqa2[m] = mkf2(q0 * a2w[9]  + q1 * a2w[12] + q2 * a2w[15],
                     q0 * a2w[10] + q1 * a2w[13] + q2 * a2w[16]);
      cqb2[m] = mkf2(q0 * a2w[11] + q1 * a2w[14] + q2 * a2w[17],
                     q0 * a2b[3]  + q1 * a2b[4]  + q2 * a2b[5]);
    }
  }
#pragma unroll
  for (int m = 0; m < 2; ++m) { d0p[m] = z2; d1p[m] = z2; d2p[m] = z2; ddp[m] = z2; }
#pragma unroll 2
  for (int u = 0; u < 16; ++u) {
    const int qid = 4 * u + s;
    const float4 P0 = *(const float4*)&sCEq[(qid * 3 + 0) * 4];
    const float4 P1 = *(const float4*)&sCEq[(qid * 3 + 1) * 4];
    const float4 P2 = *(const float4*)&sCEq[(qid * 3 + 2) * 4];
    const f2 p0l = mkf2(P0.x, P0.y), p0h = mkf2(P0.z, P0.w);
    const f2 p1l = mkf2(P1.x, P1.y), p1h = mkf2(P1.z, P1.w);
    const f2 p2l = mkf2(P2.x, P2.y), p2h = mkf2(P2.z, P2.w);
#pragma unroll
    for (int m = 0; m < 2; ++m) {
      const f2 qx = spl(cqa2[m].x), qy = spl(cqa2[m].y);
      const f2 qz = spl(cqb2[m].x), qc = spl(cqb2[m].y);
      const f2 sl = fma2(p0l, qx, fma2(p1l, qy, fma2(p2l, qz, qc)));
      const f2 sh = fma2(p0h, qx, fma2(p1h, qy, fma2(p2h, qz, qc)));
      const f2 el = mkf2(EXP2(sl.x), EXP2(sl.y));
      const f2 eh = mkf2(EXP2(sh.x), EXP2(sh.y));
      ddp[m] = ddp[m] + el + eh;
      d0p[m] = fma2(el, p0l, fma2(eh, p0h, d0p[m]));
      d1p[m] = fma2(el, p1l, fma2(eh, p1h, d1p[m]));
      d2p[m] = fma2(el, p2l, fma2(eh, p2h, d2p[m]));
    }
  }
#pragma unroll
  for (int m = 0; m < 2; ++m) {
    da0[m] = d0p[m].x + d0p[m].y; C4S(da0[m]);
    da1[m] = d1p[m].x + d1p[m].y; C4S(da1[m]);
    da2[m] = d2p[m].x + d2p[m].y; C4S(da2[m]);
    ddn[m] = ddp[m].x + ddp[m].y; C4S(ddn[m]);
  }
  {
    const float myd = sel2(ddn[0], ddn[1], ms);
    const float rdn = 1.f / myd;
    const float u0 = sel2(da0[0], da0[1], ms) * rdn;
    const float u1 = sel2(da1[0], da1[1], ms) * rdn;
    const float u2 = sel2(da2[0], da2[1], ms) * rdn;
    const float v0 = a2w[18] * u0 + a2w[19] * u1 + a2w[20] * u2 + a2b[6];
    const float v1 = a2w[21] * u0 + a2w[22] * u1 + a2w[23] * u2 + a2b[7];
    const float v2 = a2w[24] * u0 + a2w[25] * u1 + a2w[26] * u2 + a2b[8];
    r0 = a2ow[0] * v0 + a2ow[1] * v1 + a2ow[2] * v2 + a2ob[0] + x2d0;
    r1 = a2ow[3] * v0 + a2ow[4] * v1 + a2ow[5] * v2 + a2ob[1] + x2d1;
    r2 = a2ow[6] * v0 + a2ow[7] * v1 + a2ow[8] * v2 + a2ob[2] + x2d2;
  }
  block_stats(contrib ? r0 + r1 + r2 : 0.f,
              contrib ? r0 * r0 + r1 * r1 + r2 * r2 : 0.f, sRed + 24, t, 384.f, mean2, rstd2);
  const float x30 = (r0 - mean2) * rstd2 * dl1w0 + dl1b0;   // dec_ln1 AGAIN
  const float x31 = (r1 - mean2) * rstd2 * dl1w1 + dl1b1;
  const float x32 = (r2 - mean2) * rstd2 * dl1w2 + dl1b2;

  // dec FFN: both rows' x3 as h2 broadcasts (shfl + selects)
  unsigned x3x0, x3y0, x3z0, x3x1, x3y1, x3z1;
  {
    const unsigned xx = pk16(x30, x30), xy = pk16(x31, x31), xz = pk16(x32, x32);
    const int oth = (lane & ~3) + (ms ^ 1);
    const unsigned oxx = (unsigned)__shfl((int)xx, oth, 64);
    const unsigned oxy = (unsigned)__shfl((int)xy, oth, 64);
    const unsigned oxz = (unsigned)__shfl((int)xz, oth, 64);
    x3x0 = ms ? oxx : xx; x3y0 = ms ? oxy : xy; x3z0 = ms ? oxz : xz;
    x3x1 = ms ? xx : oxx; x3y1 = ms ? xy : oxy; x3z1 = ms ? xz : oxz;
  }
  float e0[2] = {0, 0}, e1[2] = {0, 0}, e2[2] = {0, 0};
#pragma unroll 4
  for (int jj = 0; jj < 64; ++jj) {
    const int pp = 4 * jj + s;
    const uint4 A = sFD[2 * pp];
    const uint4 B = sFD[2 * pp + 1];
    const h2 w1x = uph(A.x), w1y = uph(A.y), w1z = uph(A.z), b1h = uph(A.w);
    const h2 w2x = uph(B.x), w2y = uph(B.y), w2z = uph(B.z);
#pragma unroll
    for (int m = 0; m < 2; ++m) {
      h2 z = w1z * uph(m ? x3z1 : x3z0) + b1h;
      z = w1y * uph(m ? x3y1 : x3y0) + z;
      z = w1x * uph(m ? x3x1 : x3x0) + z;
      z = relu2(z);
      e0[m] = FDOT2(z, w2x, e0[m]);
      e1[m] = FDOT2(z, w2y, e1[m]);
      e2[m] = FDOT2(z, w2z, e2[m]);
    }
  }
#pragma unroll
  for (int m = 0; m < 2; ++m) { C4S(e0[m]); C4S(e1[m]); C4S(e2[m]); }

  const float f0 = sel2(e0[0], e0[1], ms) + db2[0] + x30;
  const float f1 = sel2(e1[0], e1[1], ms) + db2[1] + x31;
  const float f2v = sel2(e2[0], e2[1], ms) + db2[2] + x32;
  block_stats(contrib ? f0 + f1 + f2v : 0.f,
              contrib ? f0 * f0 + f1 * f1 + f2v * f2v : 0.f, sRed + 32, t, 384.f, mean2, rstd2);
  if (s < 2) {
    float* op = out + ((size_t)b * SPRQ + ra) * 3;
    op[0] = (f0 - mean2) * rstd2 * dln3w[lid + 0] + dln3b[lid + 0];
    op[1] = (f1 - mean2) * rstd2 * dln3w[lid + 1] + dln3b[lid + 1];
    op[2] = (f2v - mean2) * rstd2 * dln3w[lid + 2] + dln3b[lid + 2];
  }
}

extern "C" void kernel_launch(void* const* d_in, const int* in_sizes, int n_in,
                              void* d_out, int out_size, void* d_ws, size_t ws_size,
                              hipStream_t stream) {
  (void)in_sizes; (void)n_in; (void)out_size; (void)ws_size;
  float* ws = (float*)d_ws;
  uint4* fE = (uint4*)ws;                    // 8 KB
  uint4* fD = (uint4*)(ws + 2048);           // 8 KB
  float4* pe = (float4*)(ws + 4096);         // 4 KB

  pack_tabs<<<1, 256, 0, stream>>>(
      (const float*)d_in[8],  (const float*)d_in[9],  (const float*)d_in[10],
      (const float*)d_in[24], (const float*)d_in[25], (const float*)d_in[26],
      fE, fD, pe);

  fused_fwd<<<NB, 256, 0, stream>>>(
      (const float*)d_in[0],  (const float*)d_in[1],
      (const float*)d_in[2],  (const float*)d_in[3],
      (const float*)d_in[4],  (const float*)d_in[5],
      (const float*)d_in[6],  (const float*)d_in[7],
      (const float*)d_in[11],
      (const float*)d_in[12], (const float*)d_in[13],
      (const float*)d_in[14], (const float*)d_in[15],
      (const float*)d_in[16], (const float*)d_in[17],
      (const float*)d_in[18], (const float*)d_in[19],
      (const float*)d_in[20], (const float*)d_in[21],
      (const float*)d_in[22], (const float*)d_in[23],
      (const float*)d_in[27],
      (const float*)d_in[28], (const float*)d_in[29],
      fE, fD, pe,
      (float*)d_out);
}

// Round 5
// 169.828 us; speedup vs baseline: 1.0415x; 1.0228x over previous
//
#include <hip/hip_runtime.h>

#define NB   1024
#define SINQ 256
#define SPRQ 128
#define HIDQ 512

// pos_enc: emb[:, :3] = sin(pos * inv_freq[c]); inv_freq[c] = 10000^(-2c/256)
#define PEF1  0.93057207f
#define PEF2  0.86596438f
#define LOG2E 1.44269504089f
// q pre-scale: 1/sqrt(3) * log2(e)
#define QS    0.83298066476f

typedef _Float16 h2 __attribute__((ext_vector_type(2)));
typedef float    f2 __attribute__((ext_vector_type(2)));

#if defined(__has_builtin) && __has_builtin(__builtin_amdgcn_exp2f)
#define EXP2(x) __builtin_amdgcn_exp2f(x)
#else
#define EXP2(x) exp2f(x)
#endif

#if defined(__has_builtin) && __has_builtin(__builtin_amdgcn_fdot2)
#define FDOT2(a, b, c) __builtin_amdgcn_fdot2((a), (b), (c), false)
#else
__device__ __forceinline__ float fdot2_sw(h2 a, h2 b, float c) {
  return fmaf((float)a.x, (float)b.x, fmaf((float)a.y, (float)b.y, c));
}
#define FDOT2(a, b, c) fdot2_sw((a), (b), (c))
#endif

__device__ __forceinline__ unsigned pk16(float a, float b) {
  h2 v; v.x = (_Float16)a; v.y = (_Float16)b;
  return __builtin_bit_cast(unsigned, v);
}
__device__ __forceinline__ h2 uph(unsigned u) { return __builtin_bit_cast(h2, u); }

__device__ __forceinline__ h2 relu2(h2 z) {
#if defined(__has_builtin) && __has_builtin(__builtin_elementwise_max)
  h2 zz; zz.x = (_Float16)0.f; zz.y = (_Float16)0.f;
  return __builtin_elementwise_max(z, zz);
#else
  z.x = z.x > (_Float16)0.f ? z.x : (_Float16)0.f;
  z.y = z.y > (_Float16)0.f ? z.y : (_Float16)0.f;
  return z;
#endif
}

__device__ __forceinline__ f2 mkf2(float a, float b) { f2 r; r.x = a; r.y = b; return r; }
__device__ __forceinline__ f2 spl(float a) { f2 r; r.x = a; r.y = a; return r; }
#if defined(__has_builtin) && __has_builtin(__builtin_elementwise_fma)
__device__ __forceinline__ f2 fma2(f2 a, f2 b, f2 c) {
  return __builtin_elementwise_fma(a, b, c);   // v_pk_fma_f32
}
#else
__device__ __forceinline__ f2 fma2(f2 a, f2 b, f2 c) {
  f2 r; r.x = fmaf(a.x, b.x, c.x); r.y = fmaf(a.y, b.y, c.y); return r;
}
#endif

// xor-combine over the 4 slot lanes of a quad.
// NOTE: R1 post-mortem — DPP versions broke correctness; keep __shfl_xor.
#define C4S(v)  { (v) += __shfl_xor((v), 1, 64); (v) += __shfl_xor((v), 2, 64); }

// register-only selects (v_cndmask chains) -- NEVER index private arrays
// with a runtime value: that demotes them to scratch (HBM!).
__device__ __forceinline__ float sel4(float a, float b, float c, float d, int s) {
  float r = a;
  r = (s == 1) ? b : r;
  r = (s == 2) ? c : r;
  r = (s == 3) ? d : r;
  return r;
}
__device__ __forceinline__ float sel2(float a, float b, int s) {
  return s ? b : a;
}

// Block-wide (256 thr) mean/rstd over nelem values. One barrier per call:
// each call gets its own sRed slot (rotation removes the WAR pre-barrier).
__device__ __forceinline__ void block_stats(float s1, float s2, float* slot,
                                            int tid, float nelem,
                                            float& mean, float& rstd) {
#pragma unroll
  for (int off = 32; off > 0; off >>= 1) {
    s1 += __shfl_xor(s1, off, 64);
    s2 += __shfl_xor(s2, off, 64);
  }
  if ((tid & 63) == 0) {
    slot[((tid >> 6) << 1) + 0] = s1;
    slot[((tid >> 6) << 1) + 1] = s2;
  }
  __syncthreads();
  float t1 = slot[0] + slot[2] + slot[4] + slot[6];
  float t2 = slot[1] + slot[3] + slot[5] + slot[7];
  mean = t1 / nelem;
  rstd = rsqrtf(t2 / nelem - mean * mean + 1e-5f);
}

// One 256-thr block per batch element. R5: pack_tabs folded in — each block
// packs its own f16 FFN tables from global weights (L2-broadcast) and
// computes its own pos-enc sins; removes the serialized prologue kernel.
// 4-way slot-split (s = t&3) over key-QUADS: transposed LDS stores component
// c of 4 consecutive keys as one float4 (scores for 4 keys = 6 pk_fma).
__global__ __launch_bounds__(256, 4) void fused_fwd(
    const float* __restrict__ X, const float* __restrict__ T,
    const float* __restrict__ einw, const float* __restrict__ einb,
    const float* __restrict__ eow,  const float* __restrict__ eob,
    const float* __restrict__ eln1w, const float* __restrict__ eln1b,
    const float* __restrict__ eb2,
    const float* __restrict__ eln2w, const float* __restrict__ eln2b,
    const float* __restrict__ a1w, const float* __restrict__ a1b,
    const float* __restrict__ a1ow, const float* __restrict__ a1ob,
    const float* __restrict__ dln1w, const float* __restrict__ dln1b,
    const float* __restrict__ a2w, const float* __restrict__ a2b,
    const float* __restrict__ a2ow, const float* __restrict__ a2ob,
    const float* __restrict__ db2,
    const float* __restrict__ dln3w, const float* __restrict__ dln3b,
    const float* __restrict__ ew1, const float* __restrict__ eb1,
    const float* __restrict__ ew2,
    const float* __restrict__ dw1, const float* __restrict__ db1,
    const float* __restrict__ dw2,
    float* __restrict__ out)
{
  __shared__ uint4  sFE[2 * 256];                       // 8 KB enc FFN
  __shared__ uint4  sFD[2 * 256];                       // 8 KB dec FFN
  __shared__ float4 sEP[SINQ];                          // 4 KB p_X rows
  __shared__ float4 sDP[SPRQ];                          // 2 KB p_T rows
  __shared__ __align__(16) float sEPq[(SINQ / 4) * 12]; // 3 KB p_X quad-T
  __shared__ __align__(16) float sDPq[(SPRQ / 4) * 12]; // 1.5 KB p_T quad-T
  __shared__ __align__(16) float sCEq[(SINQ / 4) * 12]; // 3 KB enc_out quad-T
  __shared__ float  sRed[5 * 8];                        // per-call slots

  const int b = blockIdx.x;
  const int t = threadIdx.x;
  const int lane = t & 63;
  const int s = t & 3;             // slot
  const int g = t >> 2;            // enc row-group (0..63)

  // ---- pack FFN pair-records directly from global (was pack_tabs kernel)
  {
    const int k0 = 2 * t, k1 = 2 * t + 1;
    sFE[2 * t] = make_uint4(pk16(ew1[3 * k0], ew1[3 * k1]),
                            pk16(ew1[3 * k0 + 1], ew1[3 * k1 + 1]),
                            pk16(ew1[3 * k0 + 2], ew1[3 * k1 + 2]),
                            pk16(eb1[k0], eb1[k1]));
    sFE[2 * t + 1] = make_uint4(pk16(ew2[k0], ew2[k1]),
                                pk16(ew2[HIDQ + k0], ew2[HIDQ + k1]),
                                pk16(ew2[2 * HIDQ + k0], ew2[2 * HIDQ + k1]), 0u);
    sFD[2 * t] = make_uint4(pk16(dw1[3 * k0], dw1[3 * k1]),
                            pk16(dw1[3 * k0 + 1], dw1[3 * k1 + 1]),
                            pk16(dw1[3 * k0 + 2], dw1[3 * k1 + 2]),
                            pk16(db1[k0], db1[k1]));
    sFD[2 * t + 1] = make_uint4(pk16(dw2[k0], dw2[k1]),
                                pk16(dw2[HIDQ + k0], dw2[HIDQ + k1]),
                                pk16(dw2[2 * HIDQ + k0], dw2[2 * HIDQ + k1]), 0u);
  }
  // ---- stage p-rows (row-major AND quad-transposed); own-row pos enc sins
  {
    const float p = (float)t;
    const float pe0 = sinf(p), pe1 = sinf(p * PEF1), pe2 = sinf(p * PEF2);
    const float* xr = X + (size_t)b * SINQ * 3 + 3 * t;
    const float p0 = xr[0] + pe0, p1 = xr[1] + pe1, p2 = xr[2] + pe2;
    sEP[t] = make_float4(p0, p1, p2, 1.f);
    const int q = t >> 2, sl = t & 3;
    sEPq[(q * 3 + 0) * 4 + sl] = p0;
    sEPq[(q * 3 + 1) * 4 + sl] = p1;
    sEPq[(q * 3 + 2) * 4 + sl] = p2;
    if (t < SPRQ) {
      const float* tr = T + (size_t)b * SPRQ * 3 + 3 * t;
      const float d0 = tr[0] + pe0, d1 = tr[1] + pe1, d2 = tr[2] + pe2;
      sDP[t] = make_float4(d0, d1, d2, 1.f);
      sDPq[(q * 3 + 0) * 4 + sl] = d0;
      sDPq[(q * 3 + 1) * 4 + sl] = d1;
      sDPq[(q * 3 + 2) * 4 + sl] = d2;
    }
  }
  __syncthreads();

  const f2 z2 = mkf2(0.f, 0.f);
  float r0, r1, r2;
  float mean, rstd;

  // ================= ENCODER =================
  f2 qa2[4], qb2[4];
#pragma unroll
  for (int m = 0; m < 4; ++m) {
    const float4 pr = sEP[g + 64 * m];
    const float q0 = (einw[0] * pr.x + einw[1] * pr.y + einw[2] * pr.z + einb[0]) * QS;
    const float q1 = (einw[3] * pr.x + einw[4] * pr.y + einw[5] * pr.z + einb[1]) * QS;
    const float q2 = (einw[6] * pr.x + einw[7] * pr.y + einw[8] * pr.z + einb[2]) * QS;
    qa2[m] = mkf2(q0 * einw[9]  + q1 * einw[12] + q2 * einw[15],
                  q0 * einw[10] + q1 * einw[13] + q2 * einw[16]);
    qb2[m] = mkf2(q0 * einw[11] + q1 * einw[14] + q2 * einw[17],
                  q0 * einb[3]  + q1 * einb[4]  + q2 * einb[5]);
  }
  const int rho = g + 64 * s;
  float pr0, pr1, pr2;
  { const float4 prw = sEP[rho]; pr0 = prw.x; pr1 = prw.y; pr2 = prw.z; }

  // hoisted splatted queries (R5): loop-invariant f2 broadcasts
  f2 qxs[4], qys[4], qzs[4], qcs[4];
#pragma unroll
  for (int m = 0; m < 4; ++m) {
    qxs[m] = spl(qa2[m].x); qys[m] = spl(qa2[m].y);
    qzs[m] = spl(qb2[m].x); qcs[m] = spl(qb2[m].y);
  }

  // attention: slot s handles key-quads qid = 4*u+s (4 keys each)
  f2 a0p[4], a1p[4], a2p[4], dnp[4];
#pragma unroll
  for (int m = 0; m < 4; ++m) { a0p[m] = z2; a1p[m] = z2; a2p[m] = z2; dnp[m] = z2; }
#pragma unroll 2
  for (int u = 0; u < 16; ++u) {
    const int qid = 4 * u + s;
    const float4 P0 = *(const float4*)&sEPq[(qid * 3 + 0) * 4];
    const float4 P1 = *(const float4*)&sEPq[(qid * 3 + 1) * 4];
    const float4 P2 = *(const float4*)&sEPq[(qid * 3 + 2) * 4];
    const f2 p0l = mkf2(P0.x, P0.y), p0h = mkf2(P0.z, P0.w);
    const f2 p1l = mkf2(P1.x, P1.y), p1h = mkf2(P1.z, P1.w);
    const f2 p2l = mkf2(P2.x, P2.y), p2h = mkf2(P2.z, P2.w);
#pragma unroll
    for (int m = 0; m < 4; ++m) {
      const f2 sl = fma2(p0l, qxs[m], fma2(p1l, qys[m], fma2(p2l, qzs[m], qcs[m])));
      const f2 sh = fma2(p0h, qxs[m], fma2(p1h, qys[m], fma2(p2h, qzs[m], qcs[m])));
      const f2 el = mkf2(EXP2(sl.x), EXP2(sl.y));
      const f2 eh = mkf2(EXP2(sh.x), EXP2(sh.y));
      dnp[m] = dnp[m] + el + eh;
      a0p[m] = fma2(el, p0l, fma2(eh, p0h, a0p[m]));
      a1p[m] = fma2(el, p1l, fma2(eh, p1h, a1p[m]));
      a2p[m] = fma2(el, p2l, fma2(eh, p2h, a2p[m]));
    }
  }
  float aa0[4], aa1[4], aa2[4], adn[4];
#pragma unroll
  for (int m = 0; m < 4; ++m) {
    aa0[m] = a0p[m].x + a0p[m].y; C4S(aa0[m]);
    aa1[m] = a1p[m].x + a1p[m].y; C4S(aa1[m]);
    aa2[m] = a2p[m].x + a2p[m].y; C4S(aa2[m]);
    adn[m] = dnp[m].x + dnp[m].y; C4S(adn[m]);
  }

  {
    const float myd  = sel4(adn[0], adn[1], adn[2], adn[3], s);
    const float mya0 = sel4(aa0[0], aa0[1], aa0[2], aa0[3], s);
    const float mya1 = sel4(aa1[0], aa1[1], aa1[2], aa1[3], s);
    const float mya2 = sel4(aa2[0], aa2[1], aa2[2], aa2[3], s);
    const float rdn = 1.f / myd;
    const float u0 = mya0 * rdn, u1 = mya1 * rdn, u2 = mya2 * rdn;
    const float v0 = einw[18] * u0 + einw[19] * u1 + einw[20] * u2 + einb[6];
    const float v1 = einw[21] * u0 + einw[22] * u1 + einw[23] * u2 + einb[7];
    const float v2 = einw[24] * u0 + einw[25] * u1 + einw[26] * u2 + einb[8];
    r0 = eow[0] * v0 + eow[1] * v1 + eow[2] * v2 + eob[0] + pr0;
    r1 = eow[3] * v0 + eow[4] * v1 + eow[5] * v2 + eob[1] + pr1;
    r2 = eow[6] * v0 + eow[7] * v1 + eow[8] * v2 + eob[2] + pr2;
  }
  block_stats(r0 + r1 + r2, r0 * r0 + r1 * r1 + r2 * r2, sRed + 0, t, 768.f, mean, rstd);
  const int lie = rho * 3;
  const float x20 = (r0 - mean) * rstd * eln1w[lie + 0] + eln1b[lie + 0];
  const float x21 = (r1 - mean) * rstd * eln1w[lie + 1] + eln1b[lie + 1];
  const float x22 = (r2 - mean) * rstd * eln1w[lie + 2] + eln1b[lie + 2];

  // FFN: slot s handles pairs pp = 4*jj+s over 4 gathered rows
  unsigned xxm[4], xym[4], xzm[4];
  {
    const unsigned xx = pk16(x20, x20), xy = pk16(x21, x21), xz = pk16(x22, x22);
    const int base = lane & ~3;
#pragma unroll
    for (int m = 0; m < 4; ++m) {
      xxm[m] = (unsigned)__shfl((int)xx, base + m, 64);
      xym[m] = (unsigned)__shfl((int)xy, base + m, 64);
      xzm[m] = (unsigned)__shfl((int)xz, base + m, 64);
    }
  }
  float c0[4] = {0, 0, 0, 0}, c1[4] = {0, 0, 0, 0}, c2[4] = {0, 0, 0, 0};
#pragma unroll 4
  for (int jj = 0; jj < 64; ++jj) {
    const int pp = 4 * jj + s;
    const uint4 A = sFE[2 * pp];
    const uint4 B = sFE[2 * pp + 1];
    const h2 w1x = uph(A.x), w1y = uph(A.y), w1z = uph(A.z), b1h = uph(A.w);
    const h2 w2x = uph(B.x), w2y = uph(B.y), w2z = uph(B.z);
#pragma unroll
    for (int m = 0; m < 4; ++m) {
      h2 z = w1z * uph(xzm[m]) + b1h;
      z = w1y * uph(xym[m]) + z;
      z = w1x * uph(xxm[m]) + z;
      z = relu2(z);
      c0[m] = FDOT2(z, w2x, c0[m]);
      c1[m] = FDOT2(z, w2y, c1[m]);
      c2[m] = FDOT2(z, w2z, c2[m]);
    }
  }
#pragma unroll
  for (int m = 0; m < 4; ++m) { C4S(c0[m]); C4S(c1[m]); C4S(c2[m]); }

  const float h0 = sel4(c0[0], c0[1], c0[2], c0[3], s) + eb2[0] + x20;
  const float h1 = sel4(c1[0], c1[1], c1[2], c1[3], s) + eb2[1] + x21;
  const float h2v = sel4(c2[0], c2[1], c2[2], c2[3], s) + eb2[2] + x22;
  block_stats(h0 + h1 + h2v, h0 * h0 + h1 * h1 + h2v * h2v, sRed + 8, t, 768.f, mean, rstd);
  {
    const float e0 = (h0 - mean) * rstd * eln2w[lie + 0] + eln2b[lie + 0];
    const float e1 = (h1 - mean) * rstd * eln2w[lie + 1] + eln2b[lie + 1];
    const float e2 = (h2v - mean) * rstd * eln2w[lie + 2] + eln2b[lie + 2];
    const int q = rho >> 2, sl = rho & 3;
    sCEq[(q * 3 + 0) * 4 + sl] = e0;
    sCEq[(q * 3 + 1) * 4 + sl] = e1;
    sCEq[(q * 3 + 2) * 4 + sl] = e2;
  }
  __syncthreads();

  // ================= DECODER =================
  const int ms = s & 1;            // assigned row: ra = g + 64*ms
  const int ra = g + 64 * ms;

  f2 dqa2[2], dqb2[2];
#pragma unroll
  for (int m = 0; m < 2; ++m) {
    const float4 pr = sDP[g + 64 * m];
    const float q0 = (a1w[0] * pr.x + a1w[1] * pr.y + a1w[2] * pr.z + a1b[0]) * QS;
    const float q1 = (a1w[3] * pr.x + a1w[4] * pr.y + a1w[5] * pr.z + a1b[1]) * QS;
    const float q2 = (a1w[6] * pr.x + a1w[7] * pr.y + a1w[8] * pr.z + a1b[2]) * QS;
    dqa2[m] = mkf2(q0 * a1w[9]  + q1 * a1w[12] + q2 * a1w[15],
                   q0 * a1w[10] + q1 * a1w[13] + q2 * a1w[16]);
    dqb2[m] = mkf2(q0 * a1w[11] + q1 * a1w[14] + q2 * a1w[17],
                   q0 * a1b[3]  + q1 * a1b[4]  + q2 * a1b[5]);
  }
  float pt0, pt1, pt2;
  { const float4 prw = sDP[ra]; pt0 = prw.x; pt1 = prw.y; pt2 = prw.z; }

  // hoisted splats (R5)
  f2 dqxs[2], dqys[2], dqzs[2];
#pragma unroll
  for (int m = 0; m < 2; ++m) {
    dqxs[m] = spl(dqa2[m].x); dqys[m] = spl(dqa2[m].y); dqzs[m] = spl(dqb2[m].x);
  }

  // self-attn (additive tril(ones) mask -> +LOG2E seed when j<=row)
  f2 d0p[2], d1p[2], d2p[2], ddp[2];
#pragma unroll
  for (int m = 0; m < 2; ++m) { d0p[m] = z2; d1p[m] = z2; d2p[m] = z2; ddp[m] = z2; }
#pragma unroll 2
  for (int u = 0; u < 8; ++u) {
    const int qid = 4 * u + s;
    const int j0 = 4 * qid;
    const float4 P0 = *(const float4*)&sDPq[(qid * 3 + 0) * 4];
    const float4 P1 = *(const float4*)&sDPq[(qid * 3 + 1) * 4];
    const float4 P2 = *(const float4*)&sDPq[(qid * 3 + 2) * 4];
    const f2 p0l = mkf2(P0.x, P0.y), p0h = mkf2(P0.z, P0.w);
    const f2 p1l = mkf2(P1.x, P1.y), p1h = mkf2(P1.z, P1.w);
    const f2 p2l = mkf2(P2.x, P2.y), p2h = mkf2(P2.z, P2.w);
#pragma unroll
    for (int m = 0; m < 2; ++m) {
      const int row = g + 64 * m;
      const f2 seedl = mkf2(dqb2[m].y + (j0 + 0 <= row ? LOG2E : 0.f),
                            dqb2[m].y + (j0 + 1 <= row ? LOG2E : 0.f));
      const f2 seedh = mkf2(dqb2[m].y + (j0 + 2 <= row ? LOG2E : 0.f),
                            dqb2[m].y + (j0 + 3 <= row ? LOG2E : 0.f));
      const f2 sl = fma2(p0l, dqxs[m], fma2(p1l, dqys[m], fma2(p2l, dqzs[m], seedl)));
      const f2 sh = fma2(p0h, dqxs[m], fma2(p1h, dqys[m], fma2(p2h, dqzs[m], seedh)));
      const f2 el = mkf2(EXP2(sl.x), EXP2(sl.y));
      const f2 eh = mkf2(EXP2(sh.x), EXP2(sh.y));
      ddp[m] = ddp[m] + el + eh;
      d0p[m] = fma2(el, p0l, fma2(eh, p0h, d0p[m]));
      d1p[m] = fma2(el, p1l, fma2(eh, p1h, d1p[m]));
      d2p[m] = fma2(el, p2l, fma2(eh, p2h, d2p[m]));
    }
  }
  float da0[2], da1[2], da2[2], ddn[2];
#pragma unroll
  for (int m = 0; m < 2; ++m) {
    da0[m] = d0p[m].x + d0p[m].y; C4S(da0[m]);
    da1[m] = d1p[m].x + d1p[m].y; C4S(da1[m]);
    da2[m] = d2p[m].x + d2p[m].y; C4S(da2[m]);
    ddn[m] = ddp[m].x + ddp[m].y; C4S(ddn[m]);
  }
  {
    const float myd = sel2(ddn[0], ddn[1], ms);
    const float rdn = 1.f / myd;
    const float u0 = sel2(da0[0], da0[1], ms) * rdn;
    const float u1 = sel2(da1[0], da1[1], ms) * rdn;
    const float u2 = sel2(da2[0], da2[1], ms) * rdn;
    const float v0 = a1w[18] * u0 + a1w[19] * u1 + a1w[20] * u2 + a1b[6];
    const float v1 = a1w[21] * u0 + a1w[22] * u1 + a1w[23] * u2 + a1b[7];
    const float v2 = a1w[24] * u0 + a1w[25] * u1 + a1w[26] * u2 + a1b[8];
    r0 = a1ow[0] * v0 + a1ow[1] * v1 + a1ow[2] * v2 + a1ob[0] + pt0;
    r1 = a1ow[3] * v0 + a1ow[4] * v1 + a1ow[5] * v2 + a1ob[1] + pt1;
    r2 = a1ow[6] * v0 + a1ow[7] * v1 + a1ow[8] * v2 + a1ob[2] + pt2;
  }
  const int contrib = (s < 2) ? 1 : 0;
  float mean2, rstd2;
  block_stats(contrib ? r0 + r1 + r2 : 0.f,
              contrib ? r0 * r0 + r1 * r1 + r2 * r2 : 0.f, sRed + 16, t, 384.f, mean2, rstd2);
  const int lid = ra * 3;
  const float dl1w0 = dln1w[lid + 0], dl1w1 = dln1w[lid + 1], dl1w2 = dln1w[lid + 2];
  const float dl1b0 = dln1b[lid + 0], dl1b1 = dln1b[lid + 1], dl1b2 = dln1b[lid + 2];
  const float x2d0 = (r0 - mean2) * rstd2 * dl1w0 + dl1b0;
  const float x2d1 = (r1 - mean2) * rstd2 * dl1w1 + dl1b1;
  const float x2d2 = (r2 - mean2) * rstd2 * dl1w2 + dl1b2;

  // cross-attn queries for BOTH rows (shfl + selects; no dynamic stores)
  f2 cqa2[2], cqb2[2];
  {
    const int oth = (lane & ~3) + (ms ^ 1);
    const float ox0 = __shfl(x2d0, oth, 64);
    const float ox1 = __shfl(x2d1, oth, 64);
    const float ox2 = __shfl(x2d2, oth, 64);
    const float y00 = ms ? ox0 : x2d0;   // row m=0
    const float y01 = ms ? ox1 : x2d1;
    const float y02 = ms ? ox2 : x2d2;
    const float y10 = ms ? x2d0 : ox0;   // row m=1
    const float y11 = ms ? x2d1 : ox1;
    const float y12 = ms ? x2d2 : ox2;
#pragma unroll
    for (int m = 0; m < 2; ++m) {
      const float y0 = m ? y10 : y00, y1 = m ? y11 : y01, y2 = m ? y12 : y02;
      const float q0 = (a2w[0] * y0 + a2w[1] * y1 + a2w[2] * y2 + a2b[0]) * QS;
      const float q1 = (a2w[3] * y0 + a2w[4] * y1 + a2w[5] * y2 + a2b[1]) * QS;
      const float q2 = (a2w[6] * y0 + a2w[7] * y1 + a2w[8] * y2 + a2b[2]) * QS;
      cqa2[m] = mkf2(q0 * a2w[9]  + q1 * a2w[12] + q2 * a2w[15],
                     q0 * a2w[10] + q1 * a2w[13] + q2 * a2w[16]);
      cqb2[m] = mkf2(q0 * a2w[11] + q1 * a2w[14] + q2 * a2w[17],
                     q0 * a2b[3]  + q1 * a2b[4]  + q2 * a2b[5]);
    }
  }
  // hoisted splats (R5)
  f2 cqxs[2], cqys[2], cqzs[2], cqcs[2];
#pragma unroll
  for (int m = 0; m < 2; ++m) {
    cqxs[m] = spl(cqa2[m].x); cqys[m] = spl(cqa2[m].y);
    cqzs[m] = spl(cqb2[m].x); cqcs[m] = spl(cqb2[m].y);
  }
#pragma unroll
  for (int m = 0; m < 2; ++m) { d0p[m] = z2; d1p[m] = z2; d2p[m] = z2; ddp[m] = z2; }
#pragma unroll 2
  for (int u = 0; u < 16; ++u) {
    const int qid = 4 * u + s;
    const float4 P0 = *(const float4*)&sCEq[(qid * 3 + 0) * 4];
    const float4 P1 = *(const float4*)&sCEq[(qid * 3 + 1) * 4];
    const float4 P2 = *(const float4*)&sCEq[(qid * 3 + 2) * 4];
    const f2 p0l = mkf2(P0.x, P0.y), p0h = mkf2(P0.z, P0.w);
    const f2 p1l = mkf2(P1.x, P1.y), p1h = mkf2(P1.z, P1.w);
    const f2 p2l = mkf2(P2.x, P2.y), p2h = mkf2(P2.z, P2.w);
#pragma unroll
    for (int m = 0; m < 2; ++m) {
      const f2 sl = fma2(p0l, cqxs[m], fma2(p1l, cqys[m], fma2(p2l, cqzs[m], cqcs[m])));
      const f2 sh = fma2(p0h, cqxs[m], fma2(p1h, cqys[m], fma2(p2h, cqzs[m], cqcs[m])));
      const f2 el = mkf2(EXP2(sl.x), EXP2(sl.y));
      const f2 eh = mkf2(EXP2(sh.x), EXP2(sh.y));
      ddp[m] = ddp[m] + el + eh;
      d0p[m] = fma2(el, p0l, fma2(eh, p0h, d0p[m]));
      d1p[m] = fma2(el, p1l, fma2(eh, p1h, d1p[m]));
      d2p[m] = fma2(el, p2l, fma2(eh, p2h, d2p[m]));
    }
  }
#pragma unroll
  for (int m = 0; m < 2; ++m) {
    da0[m] = d0p[m].x + d0p[m].y; C4S(da0[m]);
    da1[m] = d1p[m].x + d1p[m].y; C4S(da1[m]);
    da2[m] = d2p[m].x + d2p[m].y; C4S(da2[m]);
    ddn[m] = ddp[m].x + ddp[m].y; C4S(ddn[m]);
  }
  {
    const float myd = sel2(ddn[0], ddn[1], ms);
    const float rdn = 1.f / myd;
    const float u0 = sel2(da0[0], da0[1], ms) * rdn;
    const float u1 = sel2(da1[0], da1[1], ms) * rdn;
    const float u2 = sel2(da2[0], da2[1], ms) * rdn;
    const float v0 = a2w[18] * u0 + a2w[19] * u1 + a2w[20] * u2 + a2b[6];
    const float v1 = a2w[21] * u0 + a2w[22] * u1 + a2w[23] * u2 + a2b[7];
    const float v2 = a2w[24] * u0 + a2w[25] * u1 + a2w[26] * u2 + a2b[8];
    r0 = a2ow[0] * v0 + a2ow[1] * v1 + a2ow[2] * v2 + a2ob[0] + x2d0;
    r1 = a2ow[3] * v0 + a2ow[4] * v1 + a2ow[5] * v2 + a2ob[1] + x2d1;
    r2 = a2ow[6] * v0 + a2ow[7] * v1 + a2ow[8] * v2 + a2ob[2] + x2d2;
  }
  block_stats(contrib ? r0 + r1 + r2 : 0.f,
              contrib ? r0 * r0 + r1 * r1 + r2 * r2 : 0.f, sRed + 24, t, 384.f, mean2, rstd2);
  const float x30 = (r0 - mean2) * rstd2 * dl1w0 + dl1b0;   // dec_ln1 AGAIN
  const float x31 = (r1 - mean2) * rstd2 * dl1w1 + dl1b1;
  const float x32 = (r2 - mean2) * rstd2 * dl1w2 + dl1b2;

  // dec FFN: both rows' x3 as h2 broadcasts (shfl + selects)
  unsigned x3x0, x3y0, x3z0, x3x1, x3y1, x3z1;
  {
    const unsigned xx = pk16(x30, x30), xy = pk16(x31, x31), xz = pk16(x32, x32);
    const int oth = (lane & ~3) + (ms ^ 1);
    const unsigned oxx = (unsigned)__shfl((int)xx, oth, 64);
    const unsigned oxy = (unsigned)__shfl((int)xy, oth, 64);
    const unsigned oxz = (unsigned)__shfl((int)xz, oth, 64);
    x3x0 = ms ? oxx : xx; x3y0 = ms ? oxy : xy; x3z0 = ms ? oxz : xz;
    x3x1 = ms ? xx : oxx; x3y1 = ms ? xy : oxy; x3z1 = ms ? xz : oxz;
  }
  float e0[2] = {0, 0}, e1[2] = {0, 0}, e2[2] = {0, 0};
#pragma unroll 4
  for (int jj = 0; jj < 64; ++jj) {
    const int pp = 4 * jj + s;
    const uint4 A = sFD[2 * pp];
    const uint4 B = sFD[2 * pp + 1];
    const h2 w1x = uph(A.x), w1y = uph(A.y), w1z = uph(A.z), b1h = uph(A.w);
    const h2 w2x = uph(B.x), w2y = uph(B.y), w2z = uph(B.z);
#pragma unroll
    for (int m = 0; m < 2; ++m) {
      h2 z = w1z * uph(m ? x3z1 : x3z0) + b1h;
      z = w1y * uph(m ? x3y1 : x3y0) + z;
      z = w1x * uph(m ? x3x1 : x3x0) + z;
      z = relu2(z);
      e0[m] = FDOT2(z, w2x, e0[m]);
      e1[m] = FDOT2(z, w2y, e1[m]);
      e2[m] = FDOT2(z, w2z, e2[m]);
    }
  }
#pragma unroll
  for (int m = 0; m < 2; ++m) { C4S(e0[m]); C4S(e1[m]); C4S(e2[m]); }

  const float f0 = sel2(e0[0], e0[1], ms) + db2[0] + x30;
  const float f1 = sel2(e1[0], e1[1], ms) + db2[1] + x31;
  const float f2v = sel2(e2[0], e2[1], ms) + db2[2] + x32;
  block_stats(contrib ? f0 + f1 + f2v : 0.f,
              contrib ? f0 * f0 + f1 * f1 + f2v * f2v : 0.f, sRed + 32, t, 384.f, mean2, rstd2);
  if (s < 2) {
    float* op = out + ((size_t)b * SPRQ + ra) * 3;
    op[0] = (f0 - mean2) * rstd2 * dln3w[lid + 0] + dln3b[lid + 0];
    op[1] = (f1 - mean2) * rstd2 * dln3w[lid + 1] + dln3b[lid + 1];
    op[2] = (f2v - mean2) * rstd2 * dln3w[lid + 2] + dln3b[lid + 2];
  }
}

extern "C" void kernel_launch(void* const* d_in, const int* in_sizes, int n_in,
                              void* d_out, int out_size, void* d_ws, size_t ws_size,
                              hipStream_t stream) {
  (void)in_sizes; (void)n_in; (void)out_size; (void)d_ws; (void)ws_size;

  fused_fwd<<<NB, 256, 0, stream>>>(
      (const float*)d_in[0],  (const float*)d_in[1],
      (const float*)d_in[2],  (const float*)d_in[3],
      (const float*)d_in[4],  (const float*)d_in[5],
      (const float*)d_in[6],  (const float*)d_in[7],
      (const float*)d_in[11],
      (const float*)d_in[12], (const float*)d_in[13],
      (const float*)d_in[14], (const float*)d_in[15],
      (const float*)d_in[16], (const float*)d_in[17],
      (const float*)d_in[18], (const float*)d_in[19],
      (const float*)d_in[20], (const float*)d_in[21],
      (const float*)d_in[22], (const float*)d_in[23],
      (const float*)d_in[27],
      (const float*)d_in[28], (const float*)d_in[29],
      (const float*)d_in[8],  (const float*)d_in[9],  (const float*)d_in[10],
      (const float*)d_in[24], (const float*)d_in[25], (const float*)d_in[26],
      (float*)d_out);
}

// Round 6
// 165.485 us; speedup vs baseline: 1.0688x; 1.0262x over previous
//
#include <hip/hip_runtime.h>

#define NB   1024
#define SINQ 256
#define SPRQ 128
#define HIDQ 512

// pos_enc: emb[:, :3] = sin(pos * inv_freq[c]); inv_freq[c] = 10000^(-2c/256)
#define PEF1  0.93057207f
#define PEF2  0.86596438f
#define LOG2E 1.44269504089f
// q pre-scale: 1/sqrt(3) * log2(e)
#define QS    0.83298066476f

typedef _Float16 h2 __attribute__((ext_vector_type(2)));
typedef float    f2 __attribute__((ext_vector_type(2)));

#if defined(__has_builtin) && __has_builtin(__builtin_amdgcn_exp2f)
#define EXP2(x) __builtin_amdgcn_exp2f(x)
#else
#define EXP2(x) exp2f(x)
#endif

#if defined(__has_builtin) && __has_builtin(__builtin_amdgcn_fdot2)
#define FDOT2(a, b, c) __builtin_amdgcn_fdot2((a), (b), (c), false)
#else
__device__ __forceinline__ float fdot2_sw(h2 a, h2 b, float c) {
  return fmaf((float)a.x, (float)b.x, fmaf((float)a.y, (float)b.y, c));
}
#define FDOT2(a, b, c) fdot2_sw((a), (b), (c))
#endif

__device__ __forceinline__ unsigned pk16(float a, float b) {
  h2 v; v.x = (_Float16)a; v.y = (_Float16)b;
  return __builtin_bit_cast(unsigned, v);
}
__device__ __forceinline__ h2 uph(unsigned u) { return __builtin_bit_cast(h2, u); }

__device__ __forceinline__ h2 relu2(h2 z) {
#if defined(__has_builtin) && __has_builtin(__builtin_elementwise_max)
  h2 zz; zz.x = (_Float16)0.f; zz.y = (_Float16)0.f;
  return __builtin_elementwise_max(z, zz);
#else
  z.x = z.x > (_Float16)0.f ? z.x : (_Float16)0.f;
  z.y = z.y > (_Float16)0.f ? z.y : (_Float16)0.f;
  return z;
#endif
}

__device__ __forceinline__ f2 mkf2(float a, float b) { f2 r; r.x = a; r.y = b; return r; }
__device__ __forceinline__ f2 spl(float a) { f2 r; r.x = a; r.y = a; return r; }
#if defined(__has_builtin) && __has_builtin(__builtin_elementwise_fma)
__device__ __forceinline__ f2 fma2(f2 a, f2 b, f2 c) {
  return __builtin_elementwise_fma(a, b, c);   // v_pk_fma_f32
}
#else
__device__ __forceinline__ f2 fma2(f2 a, f2 b, f2 c) {
  f2 r; r.x = fmaf(a.x, b.x, c.x); r.y = fmaf(a.y, b.y, c.y); return r;
}
#endif

// ---- DPP quad_perm cross-lane (R6) ---------------------------------------
// R1 post-mortem RESOLVED: the R1 DPP failure came from ROW_HALF_MIRROR
// (0x141) / ROW_MIRROR (0x140) in block_stats — those DPP controls were
// REMOVED on CDNA-lineage chips (gfx90a+ repurposed them). quad_perm
// (ctrl 0x00..0xFF) IS supported; all quad_perm sites re-derived as correct.
// So: quad-local shuffles via DPP (full-rate VALU, no LDS pipe); any
// cross-quad stride (4/8/16/32) stays __shfl_xor (ds_bpermute).
#define DPPF(x, ctrl) __builtin_bit_cast(float, __builtin_amdgcn_update_dpp( \
    0, __builtin_bit_cast(int, (x)), (ctrl), 0xF, 0xF, true))
#define DPPU(x, ctrl) ((unsigned)__builtin_amdgcn_update_dpp( \
    0, (int)(x), (ctrl), 0xF, 0xF, true))
// quad_perm controls: xor1 = (1,0,3,2) = 0xB1; xor2 = (2,3,0,1) = 0x4E;
// pair-swap (1,0,1,0) = 0x11 matches oth = (lane&~3)+(ms^1);
// quad-broadcast of lane m = m*0x55.

// xor-combine over the 4 slot lanes of a quad (DPP quad_perm).
#define C4S(v)  { (v) += DPPF((v), 0xB1); (v) += DPPF((v), 0x4E); }
#define C4F2(v) { f2 _t; _t.x = DPPF((v).x, 0xB1); _t.y = DPPF((v).y, 0xB1); (v) += _t; \
                  _t.x = DPPF((v).x, 0x4E); _t.y = DPPF((v).y, 0x4E); (v) += _t; }

// register-only selects (v_cndmask chains) -- NEVER index private arrays
// with a runtime value: that demotes them to scratch (HBM!).
__device__ __forceinline__ float sel4(float a, float b, float c, float d, int s) {
  float r = a;
  r = (s == 1) ? b : r;
  r = (s == 2) ? c : r;
  r = (s == 3) ? d : r;
  return r;
}
__device__ __forceinline__ float sel2(float a, float b, int s) {
  return s ? b : a;
}

// Block-wide (256 thr) mean/rstd over nelem values. One barrier per call:
// each call gets its own sRed slot (rotation removes the WAR pre-barrier).
// Strides 1,2 via quad_perm DPP; 4..32 via shfl (NO mirror DPP on CDNA!).
__device__ __forceinline__ void block_stats(float s1, float s2, float* slot,
                                            int tid, float nelem,
                                            float& mean, float& rstd) {
  s1 += DPPF(s1, 0xB1); s2 += DPPF(s2, 0xB1);
  s1 += DPPF(s1, 0x4E); s2 += DPPF(s2, 0x4E);
#pragma unroll
  for (int off = 32; off >= 4; off >>= 1) {
    s1 += __shfl_xor(s1, off, 64);
    s2 += __shfl_xor(s2, off, 64);
  }
  if ((tid & 63) == 0) {
    slot[((tid >> 6) << 1) + 0] = s1;
    slot[((tid >> 6) << 1) + 1] = s2;
  }
  __syncthreads();
  float t1 = slot[0] + slot[2] + slot[4] + slot[6];
  float t2 = slot[1] + slot[3] + slot[5] + slot[7];
  mean = t1 / nelem;
  rstd = rsqrtf(t2 / nelem - mean * mean + 1e-5f);
}

// One 256-thr block per batch element. pack_tabs folded in (R5): each block
// packs its own f16 FFN tables from global weights (L2-broadcast) and
// computes its own pos-enc sins. 4-way slot-split (s = t&3) over key-QUADS:
// transposed LDS stores component c of 4 consecutive keys as one float4
// (scores for 4 keys = 6 pk_fma).
__global__ __launch_bounds__(256, 4) void fused_fwd(
    const float* __restrict__ X, const float* __restrict__ T,
    const float* __restrict__ einw, const float* __restrict__ einb,
    const float* __restrict__ eow,  const float* __restrict__ eob,
    const float* __restrict__ eln1w, const float* __restrict__ eln1b,
    const float* __restrict__ eb2,
    const float* __restrict__ eln2w, const float* __restrict__ eln2b,
    const float* __restrict__ a1w, const float* __restrict__ a1b,
    const float* __restrict__ a1ow, const float* __restrict__ a1ob,
    const float* __restrict__ dln1w, const float* __restrict__ dln1b,
    const float* __restrict__ a2w, const float* __restrict__ a2b,
    const float* __restrict__ a2ow, const float* __restrict__ a2ob,
    const float* __restrict__ db2,
    const float* __restrict__ dln3w, const float* __restrict__ dln3b,
    const float* __restrict__ ew1, const float* __restrict__ eb1,
    const float* __restrict__ ew2,
    const float* __restrict__ dw1, const float* __restrict__ db1,
    const float* __restrict__ dw2,
    float* __restrict__ out)
{
  __shared__ uint4  sFE[2 * 256];                       // 8 KB enc FFN
  __shared__ uint4  sFD[2 * 256];                       // 8 KB dec FFN
  __shared__ float4 sEP[SINQ];                          // 4 KB p_X rows
  __shared__ float4 sDP[SPRQ];                          // 2 KB p_T rows
  __shared__ __align__(16) float sEPq[(SINQ / 4) * 12]; // 3 KB p_X quad-T
  __shared__ __align__(16) float sDPq[(SPRQ / 4) * 12]; // 1.5 KB p_T quad-T
  __shared__ __align__(16) float sCEq[(SINQ / 4) * 12]; // 3 KB enc_out quad-T
  __shared__ float  sRed[5 * 8];                        // per-call slots

  const int b = blockIdx.x;
  const int t = threadIdx.x;
  const int s = t & 3;             // slot
  const int g = t >> 2;            // enc row-group (0..63)

  // ---- pack FFN pair-records directly from global (was pack_tabs kernel)
  {
    const int k0 = 2 * t, k1 = 2 * t + 1;
    sFE[2 * t] = make_uint4(pk16(ew1[3 * k0], ew1[3 * k1]),
                            pk16(ew1[3 * k0 + 1], ew1[3 * k1 + 1]),
                            pk16(ew1[3 * k0 + 2], ew1[3 * k1 + 2]),
                            pk16(eb1[k0], eb1[k1]));
    sFE[2 * t + 1] = make_uint4(pk16(ew2[k0], ew2[k1]),
                                pk16(ew2[HIDQ + k0], ew2[HIDQ + k1]),
                                pk16(ew2[2 * HIDQ + k0], ew2[2 * HIDQ + k1]), 0u);
    sFD[2 * t] = make_uint4(pk16(dw1[3 * k0], dw1[3 * k1]),
                            pk16(dw1[3 * k0 + 1], dw1[3 * k1 + 1]),
                            pk16(dw1[3 * k0 + 2], dw1[3 * k1 + 2]),
                            pk16(db1[k0], db1[k1]));
    sFD[2 * t + 1] = make_uint4(pk16(dw2[k0], dw2[k1]),
                                pk16(dw2[HIDQ + k0], dw2[HIDQ + k1]),
                                pk16(dw2[2 * HIDQ + k0], dw2[2 * HIDQ + k1]), 0u);
  }
  // ---- stage p-rows (row-major AND quad-transposed); own-row pos enc sins
  {
    const float p = (float)t;
    const float pe0 = __sinf(p), pe1 = __sinf(p * PEF1), pe2 = __sinf(p * PEF2);
    const float* xr = X + (size_t)b * SINQ * 3 + 3 * t;
    const float p0 = xr[0] + pe0, p1 = xr[1] + pe1, p2 = xr[2] + pe2;
    sEP[t] = make_float4(p0, p1, p2, 1.f);
    const int q = t >> 2, sl = t & 3;
    sEPq[(q * 3 + 0) * 4 + sl] = p0;
    sEPq[(q * 3 + 1) * 4 + sl] = p1;
    sEPq[(q * 3 + 2) * 4 + sl] = p2;
    if (t < SPRQ) {
      const float* tr = T + (size_t)b * SPRQ * 3 + 3 * t;
      const float d0 = tr[0] + pe0, d1 = tr[1] + pe1, d2 = tr[2] + pe2;
      sDP[t] = make_float4(d0, d1, d2, 1.f);
      sDPq[(q * 3 + 0) * 4 + sl] = d0;
      sDPq[(q * 3 + 1) * 4 + sl] = d1;
      sDPq[(q * 3 + 2) * 4 + sl] = d2;
    }
  }
  __syncthreads();

  const f2 z2 = mkf2(0.f, 0.f);
  float r0, r1, r2;
  float mean, rstd;

  // ================= ENCODER =================
  f2 qa2[4], qb2[4];
#pragma unroll
  for (int m = 0; m < 4; ++m) {
    const float4 pr = sEP[g + 64 * m];
    const float q0 = (einw[0] * pr.x + einw[1] * pr.y + einw[2] * pr.z + einb[0]) * QS;
    const float q1 = (einw[3] * pr.x + einw[4] * pr.y + einw[5] * pr.z + einb[1]) * QS;
    const float q2 = (einw[6] * pr.x + einw[7] * pr.y + einw[8] * pr.z + einb[2]) * QS;
    qa2[m] = mkf2(q0 * einw[9]  + q1 * einw[12] + q2 * einw[15],
                  q0 * einw[10] + q1 * einw[13] + q2 * einw[16]);
    qb2[m] = mkf2(q0 * einw[11] + q1 * einw[14] + q2 * einw[17],
                  q0 * einb[3]  + q1 * einb[4]  + q2 * einb[5]);
  }
  const int rho = g + 64 * s;
  float pr0, pr1, pr2;
  { const float4 prw = sEP[rho]; pr0 = prw.x; pr1 = prw.y; pr2 = prw.z; }

  // hoisted splatted queries: loop-invariant f2 broadcasts
  f2 qxs[4], qys[4], qzs[4], qcs[4];
#pragma unroll
  for (int m = 0; m < 4; ++m) {
    qxs[m] = spl(qa2[m].x); qys[m] = spl(qa2[m].y);
    qzs[m] = spl(qb2[m].x); qcs[m] = spl(qb2[m].y);
  }

  // attention: slot s handles key-quads qid = 4*u+s (4 keys each)
  f2 a0p[4], a1p[4], a2p[4], dnp[4];
#pragma unroll
  for (int m = 0; m < 4; ++m) { a0p[m] = z2; a1p[m] = z2; a2p[m] = z2; dnp[m] = z2; }
#pragma unroll 2
  for (int u = 0; u < 16; ++u) {
    const int qid = 4 * u + s;
    const float4 P0 = *(const float4*)&sEPq[(qid * 3 + 0) * 4];
    const float4 P1 = *(const float4*)&sEPq[(qid * 3 + 1) * 4];
    const float4 P2 = *(const float4*)&sEPq[(qid * 3 + 2) * 4];
    const f2 p0l = mkf2(P0.x, P0.y), p0h = mkf2(P0.z, P0.w);
    const f2 p1l = mkf2(P1.x, P1.y), p1h = mkf2(P1.z, P1.w);
    const f2 p2l = mkf2(P2.x, P2.y), p2h = mkf2(P2.z, P2.w);
#pragma unroll
    for (int m = 0; m < 4; ++m) {
      const f2 sl = fma2(p0l, qxs[m], fma2(p1l, qys[m], fma2(p2l, qzs[m], qcs[m])));
      const f2 sh = fma2(p0h, qxs[m], fma2(p1h, qys[m], fma2(p2h, qzs[m], qcs[m])));
      const f2 el = mkf2(EXP2(sl.x), EXP2(sl.y));
      const f2 eh = mkf2(EXP2(sh.x), EXP2(sh.y));
      dnp[m] = dnp[m] + el + eh;
      a0p[m] = fma2(el, p0l, fma2(eh, p0h, a0p[m]));
      a1p[m] = fma2(el, p1l, fma2(eh, p1h, a1p[m]));
      a2p[m] = fma2(el, p2l, fma2(eh, p2h, a2p[m]));
    }
  }
  float aa0[4], aa1[4], aa2[4], adn[4];
#pragma unroll
  for (int m = 0; m < 4; ++m) {
    aa0[m] = a0p[m].x + a0p[m].y; C4S(aa0[m]);
    aa1[m] = a1p[m].x + a1p[m].y; C4S(aa1[m]);
    aa2[m] = a2p[m].x + a2p[m].y; C4S(aa2[m]);
    adn[m] = dnp[m].x + dnp[m].y; C4S(adn[m]);
  }

  {
    const float myd  = sel4(adn[0], adn[1], adn[2], adn[3], s);
    const float mya0 = sel4(aa0[0], aa0[1], aa0[2], aa0[3], s);
    const float mya1 = sel4(aa1[0], aa1[1], aa1[2], aa1[3], s);
    const float mya2 = sel4(aa2[0], aa2[1], aa2[2], aa2[3], s);
    const float rdn = 1.f / myd;
    const float u0 = mya0 * rdn, u1 = mya1 * rdn, u2 = mya2 * rdn;
    const float v0 = einw[18] * u0 + einw[19] * u1 + einw[20] * u2 + einb[6];
    const float v1 = einw[21] * u0 + einw[22] * u1 + einw[23] * u2 + einb[7];
    const float v2 = einw[24] * u0 + einw[25] * u1 + einw[26] * u2 + einb[8];
    r0 = eow[0] * v0 + eow[1] * v1 + eow[2] * v2 + eob[0] + pr0;
    r1 = eow[3] * v0 + eow[4] * v1 + eow[5] * v2 + eob[1] + pr1;
    r2 = eow[6] * v0 + eow[7] * v1 + eow[8] * v2 + eob[2] + pr2;
  }
  block_stats(r0 + r1 + r2, r0 * r0 + r1 * r1 + r2 * r2, sRed + 0, t, 768.f, mean, rstd);
  const int lie = rho * 3;
  const float x20 = (r0 - mean) * rstd * eln1w[lie + 0] + eln1b[lie + 0];
  const float x21 = (r1 - mean) * rstd * eln1w[lie + 1] + eln1b[lie + 1];
  const float x22 = (r2 - mean) * rstd * eln1w[lie + 2] + eln1b[lie + 2];

  // FFN: slot s handles pairs pp = 4*jj+s over 4 quad-gathered rows (DPP bcast)
  unsigned xxm[4], xym[4], xzm[4];
  {
    const unsigned xx = pk16(x20, x20), xy = pk16(x21, x21), xz = pk16(x22, x22);
    xxm[0] = DPPU(xx, 0x00); xym[0] = DPPU(xy, 0x00); xzm[0] = DPPU(xz, 0x00);
    xxm[1] = DPPU(xx, 0x55); xym[1] = DPPU(xy, 0x55); xzm[1] = DPPU(xz, 0x55);
    xxm[2] = DPPU(xx, 0xAA); xym[2] = DPPU(xy, 0xAA); xzm[2] = DPPU(xz, 0xAA);
    xxm[3] = DPPU(xx, 0xFF); xym[3] = DPPU(xy, 0xFF); xzm[3] = DPPU(xz, 0xFF);
  }
  float c0[4] = {0, 0, 0, 0}, c1[4] = {0, 0, 0, 0}, c2[4] = {0, 0, 0, 0};
#pragma unroll 4
  for (int jj = 0; jj < 64; ++jj) {
    const int pp = 4 * jj + s;
    const uint4 A = sFE[2 * pp];
    const uint4 B = sFE[2 * pp + 1];
    const h2 w1x = uph(A.x), w1y = uph(A.y), w1z = uph(A.z), b1h = uph(A.w);
    const h2 w2x = uph(B.x), w2y = uph(B.y), w2z = uph(B.z);
#pragma unroll
    for (int m = 0; m < 4; ++m) {
      h2 z = w1z * uph(xzm[m]) + b1h;
      z = w1y * uph(xym[m]) + z;
      z = w1x * uph(xxm[m]) + z;
      z = relu2(z);
      c0[m] = FDOT2(z, w2x, c0[m]);
      c1[m] = FDOT2(z, w2y, c1[m]);
      c2[m] = FDOT2(z, w2z, c2[m]);
    }
  }
#pragma unroll
  for (int m = 0; m < 4; ++m) { C4S(c0[m]); C4S(c1[m]); C4S(c2[m]); }

  const float h0 = sel4(c0[0], c0[1], c0[2], c0[3], s) + eb2[0] + x20;
  const float h1 = sel4(c1[0], c1[1], c1[2], c1[3], s) + eb2[1] + x21;
  const float h2v = sel4(c2[0], c2[1], c2[2], c2[3], s) + eb2[2] + x22;
  block_stats(h0 + h1 + h2v, h0 * h0 + h1 * h1 + h2v * h2v, sRed + 8, t, 768.f, mean, rstd);
  {
    const float e0 = (h0 - mean) * rstd * eln2w[lie + 0] + eln2b[lie + 0];
    const float e1 = (h1 - mean) * rstd * eln2w[lie + 1] + eln2b[lie + 1];
    const float e2 = (h2v - mean) * rstd * eln2w[lie + 2] + eln2b[lie + 2];
    const int q = rho >> 2, sl = rho & 3;
    sCEq[(q * 3 + 0) * 4 + sl] = e0;
    sCEq[(q * 3 + 1) * 4 + sl] = e1;
    sCEq[(q * 3 + 2) * 4 + sl] = e2;
  }
  __syncthreads();

  // ================= DECODER =================
  const int ms = s & 1;            // assigned row: ra = g + 64*ms
  const int ra = g + 64 * ms;

  f2 dqa2[2], dqb2[2];
#pragma unroll
  for (int m = 0; m < 2; ++m) {
    const float4 pr = sDP[g + 64 * m];
    const float q0 = (a1w[0] * pr.x + a1w[1] * pr.y + a1w[2] * pr.z + a1b[0]) * QS;
    const float q1 = (a1w[3] * pr.x + a1w[4] * pr.y + a1w[5] * pr.z + a1b[1]) * QS;
    const float q2 = (a1w[6] * pr.x + a1w[7] * pr.y + a1w[8] * pr.z + a1b[2]) * QS;
    dqa2[m] = mkf2(q0 * a1w[9]  + q1 * a1w[12] + q2 * a1w[15],
                   q0 * a1w[10] + q1 * a1w[13] + q2 * a1w[16]);
    dqb2[m] = mkf2(q0 * a1w[11] + q1 * a1w[14] + q2 * a1w[17],
                   q0 * a1b[3]  + q1 * a1b[4]  + q2 * a1b[5]);
  }
  float pt0, pt1, pt2;
  { const float4 prw = sDP[ra]; pt0 = prw.x; pt1 = prw.y; pt2 = prw.z; }

  // hoisted splats
  f2 dqxs[2], dqys[2], dqzs[2];
#pragma unroll
  for (int m = 0; m < 2; ++m) {
    dqxs[m] = spl(dqa2[m].x); dqys[m] = spl(dqa2[m].y); dqzs[m] = spl(dqb2[m].x);
  }

  // self-attn (additive tril(ones) mask -> +LOG2E seed when j<=row)
  f2 d0p[2], d1p[2], d2p[2], ddp[2];
#pragma unroll
  for (int m = 0; m < 2; ++m) { d0p[m] = z2; d1p[m] = z2; d2p[m] = z2; ddp[m] = z2; }
#pragma unroll 2
  for (int u = 0; u < 8; ++u) {
    const int qid = 4 * u + s;
    const int j0 = 4 * qid;
    const float4 P0 = *(const float4*)&sDPq[(qid * 3 + 0) * 4];
    const float4 P1 = *(const float4*)&sDPq[(qid * 3 + 1) * 4];
    const float4 P2 = *(const float4*)&sDPq[(qid * 3 + 2) * 4];
    const f2 p0l = mkf2(P0.x, P0.y), p0h = mkf2(P0.z, P0.w);
    const f2 p1l = mkf2(P1.x, P1.y), p1h = mkf2(P1.z, P1.w);
    const f2 p2l = mkf2(P2.x, P2.y), p2h = mkf2(P2.z, P2.w);
#pragma unroll
    for (int m = 0; m < 2; ++m) {
      const int row = g + 64 * m;
      const f2 seedl = mkf2(dqb2[m].y + (j0 + 0 <= row ? LOG2E : 0.f),
                            dqb2[m].y + (j0 + 1 <= row ? LOG2E : 0.f));
      const f2 seedh = mkf2(dqb2[m].y + (j0 + 2 <= row ? LOG2E : 0.f),
                            dqb2[m].y + (j0 + 3 <= row ? LOG2E : 0.f));
      const f2 sl = fma2(p0l, dqxs[m], fma2(p1l, dqys[m], fma2(p2l, dqzs[m], seedl)));
      const f2 sh = fma2(p0h, dqxs[m], fma2(p1h, dqys[m], fma2(p2h, dqzs[m], seedh)));
      const f2 el = mkf2(EXP2(sl.x), EXP2(sl.y));
      const f2 eh = mkf2(EXP2(sh.x), EXP2(sh.y));
      ddp[m] = ddp[m] + el + eh;
      d0p[m] = fma2(el, p0l, fma2(eh, p0h, d0p[m]));
      d1p[m] = fma2(el, p1l, fma2(eh, p1h, d1p[m]));
      d2p[m] = fma2(el, p2l, fma2(eh, p2h, d2p[m]));
    }
  }
  float da0[2], da1[2], da2[2], ddn[2];
#pragma unroll
  for (int m = 0; m < 2; ++m) {
    da0[m] = d0p[m].x + d0p[m].y; C4S(da0[m]);
    da1[m] = d1p[m].x + d1p[m].y; C4S(da1[m]);
    da2[m] = d2p[m].x + d2p[m].y; C4S(da2[m]);
    ddn[m] = ddp[m].x + ddp[m].y; C4S(ddn[m]);
  }
  {
    const float myd = sel2(ddn[0], ddn[1], ms);
    const float rdn = 1.f / myd;
    const float u0 = sel2(da0[0], da0[1], ms) * rdn;
    const float u1 = sel2(da1[0], da1[1], ms) * rdn;
    const float u2 = sel2(da2[0], da2[1], ms) * rdn;
    const float v0 = a1w[18] * u0 + a1w[19] * u1 + a1w[20] * u2 + a1b[6];
    const float v1 = a1w[21] * u0 + a1w[22] * u1 + a1w[23] * u2 + a1b[7];
    const float v2 = a1w[24] * u0 + a1w[25] * u1 + a1w[26] * u2 + a1b[8];
    r0 = a1ow[0] * v0 + a1ow[1] * v1 + a1ow[2] * v2 + a1ob[0] + pt0;
    r1 = a1ow[3] * v0 + a1ow[4] * v1 + a1ow[5] * v2 + a1ob[1] + pt1;
    r2 = a1ow[6] * v0 + a1ow[7] * v1 + a1ow[8] * v2 + a1ob[2] + pt2;
  }
  const int contrib = (s < 2) ? 1 : 0;
  float mean2, rstd2;
  block_stats(contrib ? r0 + r1 + r2 : 0.f,
              contrib ? r0 * r0 + r1 * r1 + r2 * r2 : 0.f, sRed + 16, t, 384.f, mean2, rstd2);
  const int lid = ra * 3;
  const float dl1w0 = dln1w[lid + 0], dl1w1 = dln1w[lid + 1], dl1w2 = dln1w[lid + 2];
  const float dl1b0 = dln1b[lid + 0], dl1b1 = dln1b[lid + 1], dl1b2 = dln1b[lid + 2];
  const float x2d0 = (r0 - mean2) * rstd2 * dl1w0 + dl1b0;
  const float x2d1 = (r1 - mean2) * rstd2 * dl1w1 + dl1b1;
  const float x2d2 = (r2 - mean2) * rstd2 * dl1w2 + dl1b2;

  // cross-attn queries for BOTH rows (DPP pair-swap 0x11 + selects)
  f2 cqa2[2], cqb2[2];
  {
    const float ox0 = DPPF(x2d0, 0x11);
    const float ox1 = DPPF(x2d1, 0x11);
    const float ox2 = DPPF(x2d2, 0x11);
    const float y00 = ms ? ox0 : x2d0;   // row m=0
    const float y01 = ms ? ox1 : x2d1;
    const float y02 = ms ? ox2 : x2d2;
    const float y10 = ms ? x2d0 : ox0;   // row m=1
    const float y11 = ms ? x2d1 : ox1;
    const float y12 = ms ? x2d2 : ox2;
#pragma unroll
    for (int m = 0; m < 2; ++m) {
      const float y0 = m ? y10 : y00, y1 = m ? y11 : y01, y2 = m ? y12 : y02;
      const float q0 = (a2w[0] * y0 + a2w[1] * y1 + a2w[2] * y2 + a2b[0]) * QS;
      const float q1 = (a2w[3] * y0 + a2w[4] * y1 + a2w[5] * y2 + a2b[1]) * QS;
      const float q2 = (a2w[6] * y0 + a2w[7] * y1 + a2w[8] * y2 + a2b[2]) * QS;
      cqa2[m] = mkf2(q0 * a2w[9]  + q1 * a2w[12] + q2 * a2w[15],
                     q0 * a2w[10] + q1 * a2w[13] + q2 * a2w[16]);
      cqb2[m] = mkf2(q0 * a2w[11] + q1 * a2w[14] + q2 * a2w[17],
                     q0 * a2b[3]  + q1 * a2b[4]  + q2 * a2b[5]);
    }
  }
  // hoisted splats
  f2 cqxs[2], cqys[2], cqzs[2], cqcs[2];
#pragma unroll
  for (int m = 0; m < 2; ++m) {
    cqxs[m] = spl(cqa2[m].x); cqys[m] = spl(cqa2[m].y);
    cqzs[m] = spl(cqb2[m].x); cqcs[m] = spl(cqb2[m].y);
  }
#pragma unroll
  for (int m = 0; m < 2; ++m) { d0p[m] = z2; d1p[m] = z2; d2p[m] = z2; ddp[m] = z2; }
#pragma unroll 2
  for (int u = 0; u < 16; ++u) {
    const int qid = 4 * u + s;
    const float4 P0 = *(const float4*)&sCEq[(qid * 3 + 0) * 4];
    const float4 P1 = *(const float4*)&sCEq[(qid * 3 + 1) * 4];
    const float4 P2 = *(const float4*)&sCEq[(qid * 3 + 2) * 4];
    const f2 p0l = mkf2(P0.x, P0.y), p0h = mkf2(P0.z, P0.w);
    const f2 p1l = mkf2(P1.x, P1.y), p1h = mkf2(P1.z, P1.w);
    const f2 p2l = mkf2(P2.x, P2.y), p2h = mkf2(P2.z, P2.w);
#pragma unroll
    for (int m = 0; m < 2; ++m) {
      const f2 sl = fma2(p0l, cqxs[m], fma2(p1l, cqys[m], fma2(p2l, cqzs[m], cqcs[m])));
      const f2 sh = fma2(p0h, cqxs[m], fma2(p1h, cqys[m], fma2(p2h, cqzs[m], cqcs[m])));
      const f2 el = mkf2(EXP2(sl.x), EXP2(sl.y));
      const f2 eh = mkf2(EXP2(sh.x), EXP2(sh.y));
      ddp[m] = ddp[m] + el + eh;
      d0p[m] = fma2(el, p0l, fma2(eh, p0h, d0p[m]));
      d1p[m] = fma2(el, p1l, fma2(eh, p1h, d1p[m]));
      d2p[m] = fma2(el, p2l, fma2(eh, p2h, d2p[m]));
    }
  }
#pragma unroll
  for (int m = 0; m < 2; ++m) {
    da0[m] = d0p[m].x + d0p[m].y; C4S(da0[m]);
    da1[m] = d1p[m].x + d1p[m].y; C4S(da1[m]);
    da2[m] = d2p[m].x + d2p[m].y; C4S(da2[m]);
    ddn[m] = ddp[m].x + ddp[m].y; C4S(ddn[m]);
  }
  {
    const float myd = sel2(ddn[0], ddn[1], ms);
    const float rdn = 1.f / myd;
    const float u0 = sel2(da0[0], da0[1], ms) * rdn;
    const float u1 = sel2(da1[0], da1[1], ms) * rdn;
    const float u2 = sel2(da2[0], da2[1], ms) * rdn;
    const float v0 = a2w[18] * u0 + a2w[19] * u1 + a2w[20] * u2 + a2b[6];
    const float v1 = a2w[21] * u0 + a2w[22] * u1 + a2w[23] * u2 + a2b[7];
    const float v2 = a2w[24] * u0 + a2w[25] * u1 + a2w[26] * u2 + a2b[8];
    r0 = a2ow[0] * v0 + a2ow[1] * v1 + a2ow[2] * v2 + a2ob[0] + x2d0;
    r1 = a2ow[3] * v0 + a2ow[4] * v1 + a2ow[5] * v2 + a2ob[1] + x2d1;
    r2 = a2ow[6] * v0 + a2ow[7] * v1 + a2ow[8] * v2 + a2ob[2] + x2d2;
  }
  block_stats(contrib ? r0 + r1 + r2 : 0.f,
              contrib ? r0 * r0 + r1 * r1 + r2 * r2 : 0.f, sRed + 24, t, 384.f, mean2, rstd2);
  const float x30 = (r0 - mean2) * rstd2 * dl1w0 + dl1b0;   // dec_ln1 AGAIN
  const float x31 = (r1 - mean2) * rstd2 * dl1w1 + dl1b1;
  const float x32 = (r2 - mean2) * rstd2 * dl1w2 + dl1b2;

  // dec FFN: both rows' x3 as h2 broadcasts (DPP pair-swap + selects)
  unsigned x3x0, x3y0, x3z0, x3x1, x3y1, x3z1;
  {
    const unsigned xx = pk16(x30, x30), xy = pk16(x31, x31), xz = pk16(x32, x32);
    const unsigned oxx = DPPU(xx, 0x11);
    const unsigned oxy = DPPU(xy, 0x11);
    const unsigned oxz = DPPU(xz, 0x11);
    x3x0 = ms ? oxx : xx; x3y0 = ms ? oxy : xy; x3z0 = ms ? oxz : xz;
    x3x1 = ms ? xx : oxx; x3y1 = ms ? xy : oxy; x3z1 = ms ? xz : oxz;
  }
  float e0[2] = {0, 0}, e1[2] = {0, 0}, e2[2] = {0, 0};
#pragma unroll 4
  for (int jj = 0; jj < 64; ++jj) {
    const int pp = 4 * jj + s;
    const uint4 A = sFD[2 * pp];
    const uint4 B = sFD[2 * pp + 1];
    const h2 w1x = uph(A.x), w1y = uph(A.y), w1z = uph(A.z), b1h = uph(A.w);
    const h2 w2x = uph(B.x), w2y = uph(B.y), w2z = uph(B.z);
#pragma unroll
    for (int m = 0; m < 2; ++m) {
      h2 z = w1z * uph(m ? x3z1 : x3z0) + b1h;
      z = w1y * uph(m ? x3y1 : x3y0) + z;
      z = w1x * uph(m ? x3x1 : x3x0) + z;
      z = relu2(z);
      e0[m] = FDOT2(z, w2x, e0[m]);
      e1[m] = FDOT2(z, w2y, e1[m]);
      e2[m] = FDOT2(z, w2z, e2[m]);
    }
  }
#pragma unroll
  for (int m = 0; m < 2; ++m) { C4S(e0[m]); C4S(e1[m]); C4S(e2[m]); }

  const float f0 = sel2(e0[0], e0[1], ms) + db2[0] + x30;
  const float f1 = sel2(e1[0], e1[1], ms) + db2[1] + x31;
  const float f2v = sel2(e2[0], e2[1], ms) + db2[2] + x32;
  block_stats(contrib ? f0 + f1 + f2v : 0.f,
              contrib ? f0 * f0 + f1 * f1 + f2v * f2v : 0.f, sRed + 32, t, 384.f, mean2, rstd2);
  if (s < 2) {
    float* op = out + ((size_t)b * SPRQ + ra) * 3;
    op[0] = (f0 - mean2) * rstd2 * dln3w[lid + 0] + dln3b[lid + 0];
    op[1] = (f1 - mean2) * rstd2 * dln3w[lid + 1] + dln3b[lid + 1];
    op[2] = (f2v - mean2) * rstd2 * dln3w[lid + 2] + dln3b[lid + 2];
  }
}

extern "C" void kernel_launch(void* const* d_in, const int* in_sizes, int n_in,
                              void* d_out, int out_size, void* d_ws, size_t ws_size,
                              hipStream_t stream) {
  (void)in_sizes; (void)n_in; (void)out_size; (void)d_ws; (void)ws_size;

  fused_fwd<<<NB, 256, 0, stream>>>(
      (const float*)d_in[0],  (const float*)d_in[1],
      (const float*)d_in[2],  (const float*)d_in[3],
      (const float*)d_in[4],  (const float*)d_in[5],
      (const float*)d_in[6],  (const float*)d_in[7],
      (const float*)d_in[11],
      (const float*)d_in[12], (const float*)d_in[13],
      (const float*)d_in[14], (const float*)d_in[15],
      (const float*)d_in[16], (const float*)d_in[17],
      (const float*)d_in[18], (const float*)d_in[19],
      (const float*)d_in[20], (const float*)d_in[21],
      (const float*)d_in[22], (const float*)d_in[23],
      (const float*)d_in[27],
      (const float*)d_in[28], (const float*)d_in[29],
      (const float*)d_in[8],  (const float*)d_in[9],  (const float*)d_in[10],
      (const float*)d_in[24], (const float*)d_in[25], (const float*)d_in[26],
      (float*)d_out);
}